// Round 6
// baseline (593.365 us; speedup 1.0000x reference)
//
#include <hip/hip_runtime.h>
#include <cstddef>

// Problem constants (from reference)
static constexpr int Nn    = 20000;
static constexpr int Ee    = 320000;
static constexpr int Vv    = 100;
static constexpr int Hh    = 128;
static constexpr int HEADS = 3;
static constexpr int Bb    = 200;
static constexpr float NEG = 0.2f;
static constexpr float EPS = 1e-5f;

typedef short bf16x8 __attribute__((ext_vector_type(8)));
typedef float f32x4  __attribute__((ext_vector_type(4)));

__device__ inline unsigned short bf16_rne(float x) {
    unsigned u = __builtin_bit_cast(unsigned, x);
    u += 0x7FFFu + ((u >> 16) & 1u);
    return (unsigned short)(u >> 16);
}
__device__ inline float bf16_f(unsigned short h) {
    unsigned u = ((unsigned)h) << 16;
    return __builtin_bit_cast(float, u);
}
__device__ inline float bf_lo(unsigned u) { return __builtin_bit_cast(float, u << 16); }
__device__ inline float bf_hi(unsigned u) { return __builtin_bit_cast(float, u & 0xFFFF0000u); }
__device__ inline float lrelu(float a) { return a >= 0.f ? a : NEG * a; }
__device__ inline float sigmoidf(float x) { return 1.f / (1.f + __expf(-x)); }

// ---------------------------------------------------------------------------
// CSR build: histogram over dst, single-block scan, fill (stores src ids)
// ---------------------------------------------------------------------------
__global__ void hist_dst(const int* __restrict__ dst, int* __restrict__ deg) {
    for (int i = blockIdx.x * blockDim.x + threadIdx.x; i < Ee; i += gridDim.x * blockDim.x)
        atomicAdd(&deg[dst[i]], 1);
}

__global__ __launch_bounds__(1024) void scan_offsets(const int* __restrict__ deg,
                                                     int* __restrict__ offs,
                                                     int* __restrict__ cur) {
    __shared__ int sums[1024];
    const int tid = threadIdx.x;
    const int per = (Nn + 1023) >> 10;          // 20
    int begin = tid * per;
    int end = begin + per; if (end > Nn) end = Nn;
    if (begin > Nn) begin = Nn;
    int s = 0;
    for (int i = begin; i < end; i++) s += deg[i];
    sums[tid] = s;
    __syncthreads();
    for (int off = 1; off < 1024; off <<= 1) {
        int v = (tid >= off) ? sums[tid - off] : 0;
        __syncthreads();
        sums[tid] += v;
        __syncthreads();
    }
    int run = sums[tid] - s;                    // exclusive prefix
    for (int i = begin; i < end; i++) {
        offs[i] = run; cur[i] = run;
        run += deg[i];
    }
    if (end == Nn) offs[Nn] = run;
}

__global__ void fill_csr(const int* __restrict__ dst, const int* __restrict__ src,
                         int* __restrict__ cur, int* __restrict__ csrc) {
    for (int i = blockIdx.x * blockDim.x + threadIdx.x; i < Ee; i += gridDim.x * blockDim.x) {
        int p = atomicAdd(&cur[dst[i]], 1);
        csrc[p] = src[i];
    }
}

// ---------------------------------------------------------------------------
// graph_ids is SORTED (reference setup uses jnp.sort) -> segment boundaries.
// goffs[b] = first node index with gid >= b; graph b = [goffs[b], goffs[b+1]).
// ---------------------------------------------------------------------------
__global__ void graph_offsets(const int* __restrict__ gid, int* __restrict__ goffs) {
    int i = blockIdx.x * blockDim.x + threadIdx.x;
    if (i >= Nn) return;
    int g = gid[i];
    if (i == 0) {
        for (int b = 0; b <= g; b++) goffs[b] = 0;
    } else {
        int pg = gid[i - 1];
        for (int b = pg + 1; b <= g; b++) goffs[b] = i;
    }
    if (i == Nn - 1) {
        for (int b = g + 1; b <= Bb; b++) goffs[b] = Nn;
    }
}

// Per-graph mean over contiguous node range (no atomics).
__global__ __launch_bounds__(128) void readout_mean(const float* __restrict__ hcur,
                                                    const int* __restrict__ goffs,
                                                    float* __restrict__ reado_t) {
    const int b = blockIdx.x, j = threadIdx.x;
    const int s = goffs[b], e = goffs[b + 1];
    float acc = 0.f;
    for (int n = s; n < e; n++) acc += hcur[(size_t)n * Hh + j];
    float inv = (e > s) ? 1.f / (float)(e - s) : 0.f;
    reado_t[(size_t)b * Hh + j] = acc * inv;
}

// ---------------------------------------------------------------------------
// Fused weight prep (one launch)
// ---------------------------------------------------------------------------
struct PrepArgs {
    const float *projW, *convWn, *convWs, *Wih0, *Whh0, *Wih1, *Whh1;
    unsigned short *pBth, *pBtl;
    unsigned short *WnTh0, *WnTl0, *WnTh1, *WnTl1;
    unsigned short *WsTh0, *WsTl0, *WsTh1, *WsTl1;
    float *WihT0, *WhhT0, *WihT1, *WhhT1;
};

__device__ inline void wsplit(const float* B, int K, int N, int idx,
                              unsigned short* Bth, unsigned short* Btl) {
    int k = idx / N, n = idx - k * N;
    float v = B[idx];
    unsigned short h = bf16_rne(v);
    unsigned short l = bf16_rne(v - bf16_f(h));
    Bth[(size_t)n * K + k] = h;
    Btl[(size_t)n * K + k] = l;
}
__device__ inline void gruT(const float* W, int K, int idx, float* WT) {
    int d = idx / (384 * K);
    int r = idx - d * 384 * K;
    int j = r / K, k = r - j * K;
    WT[(size_t)d * K * 384 + (size_t)k * 384 + j] = W[idx];
}

__global__ void prep_all(PrepArgs a) {
    int i = blockIdx.x * blockDim.x + threadIdx.x;
    if (i < 16384)  { wsplit(a.projW, 128, 128, i, a.pBth, a.pBtl); return; }   i -= 16384;
    if (i < 49152)  { wsplit(a.convWn, 128, 384, i, a.WnTh0, a.WnTl0); return; } i -= 49152;
    if (i < 49152)  { wsplit(a.convWn + 49152, 128, 384, i, a.WnTh1, a.WnTl1); return; } i -= 49152;
    if (i < 49152)  { wsplit(a.convWs, 384, 128, i, a.WsTh0, a.WsTl0); return; } i -= 49152;
    if (i < 49152)  { wsplit(a.convWs + 49152, 384, 128, i, a.WsTh1, a.WsTl1); return; } i -= 49152;
    if (i < 98304)  { gruT(a.Wih0, 128, i, a.WihT0); return; }  i -= 98304;
    if (i < 98304)  { gruT(a.Whh0, 128, i, a.WhhT0); return; }  i -= 98304;
    if (i < 196608) { gruT(a.Wih1, 256, i, a.WihT1); return; }  i -= 196608;
    if (i < 98304)  { gruT(a.Whh1, 128, i, a.WhhT1); }
}

// ---------------------------------------------------------------------------
// Split-bf16 MFMA GEMM core. BM=128, BN=128, BK=32; 256 threads (2x2 waves),
// wave tile 64x64 (4x4 MFMA 16x16x32). OUT_BF16 selects fp32 or bf16 C.
// ---------------------------------------------------------------------------
template <bool OUT_BF16>
__global__ __launch_bounds__(256) void gemm_mfma_t(const float* __restrict__ A,
                                                   const unsigned short* __restrict__ Bth,
                                                   const unsigned short* __restrict__ Btl,
                                                   const float* __restrict__ bias,
                                                   float* __restrict__ C,
                                                   unsigned short* __restrict__ Cb,
                                                   int M, int N, int K) {
    __shared__ unsigned short As_hi[128][40];
    __shared__ unsigned short As_lo[128][40];
    __shared__ unsigned short Bs_hi[128][40];
    __shared__ unsigned short Bs_lo[128][40];
    const int tid  = threadIdx.x;
    const int row0 = blockIdx.y * 128;
    const int col0 = blockIdx.x * 128;
    const int w    = tid >> 6;
    const int wm   = w >> 1;
    const int wn   = w & 1;
    const int L    = tid & 63;
    const int lrow = L & 15;
    const int lq   = L >> 4;

    f32x4 acc[4][4];
#pragma unroll
    for (int i = 0; i < 4; i++)
#pragma unroll
        for (int j = 0; j < 4; j++) acc[i][j] = (f32x4){0.f, 0.f, 0.f, 0.f};

    for (int kb = 0; kb < K; kb += 32) {
#pragma unroll
        for (int it = 0; it < 4; it++) {
            int idx = tid + it * 256;
            int m  = idx >> 3;
            int kq = (idx & 7) * 4;
            int gr = row0 + m;
            float4 v = make_float4(0.f, 0.f, 0.f, 0.f);
            if (gr < M) v = *(const float4*)(A + (size_t)gr * K + kb + kq);
            unsigned short h0 = bf16_rne(v.x), h1 = bf16_rne(v.y),
                           h2 = bf16_rne(v.z), h3 = bf16_rne(v.w);
            short4 hi4 = make_short4((short)h0, (short)h1, (short)h2, (short)h3);
            short4 lo4 = make_short4((short)bf16_rne(v.x - bf16_f(h0)),
                                     (short)bf16_rne(v.y - bf16_f(h1)),
                                     (short)bf16_rne(v.z - bf16_f(h2)),
                                     (short)bf16_rne(v.w - bf16_f(h3)));
            *(short4*)&As_hi[m][kq] = hi4;
            *(short4*)&As_lo[m][kq] = lo4;
        }
        {
            int n  = tid >> 1;
            int kh = (tid & 1) * 16;
            const unsigned short* sh = Bth + (size_t)(col0 + n) * K + kb + kh;
            const unsigned short* sl = Btl + (size_t)(col0 + n) * K + kb + kh;
            *(float4*)&Bs_hi[n][kh]     = *(const float4*)sh;
            *(float4*)&Bs_hi[n][kh + 8] = *(const float4*)(sh + 8);
            *(float4*)&Bs_lo[n][kh]     = *(const float4*)sl;
            *(float4*)&Bs_lo[n][kh + 8] = *(const float4*)(sl + 8);
        }
        __syncthreads();
        bf16x8 ah[4], al[4], bh[4], bl[4];
#pragma unroll
        for (int mi = 0; mi < 4; mi++) {
            int r = wm * 64 + mi * 16 + lrow;
            ah[mi] = *(const bf16x8*)&As_hi[r][lq * 8];
            al[mi] = *(const bf16x8*)&As_lo[r][lq * 8];
        }
#pragma unroll
        for (int ni = 0; ni < 4; ni++) {
            int r = wn * 64 + ni * 16 + lrow;
            bh[ni] = *(const bf16x8*)&Bs_hi[r][lq * 8];
            bl[ni] = *(const bf16x8*)&Bs_lo[r][lq * 8];
        }
#pragma unroll
        for (int mi = 0; mi < 4; mi++)
#pragma unroll
            for (int ni = 0; ni < 4; ni++) {
                acc[mi][ni] = __builtin_amdgcn_mfma_f32_16x16x32_bf16(ah[mi], bh[ni], acc[mi][ni], 0, 0, 0);
                acc[mi][ni] = __builtin_amdgcn_mfma_f32_16x16x32_bf16(ah[mi], bl[ni], acc[mi][ni], 0, 0, 0);
                acc[mi][ni] = __builtin_amdgcn_mfma_f32_16x16x32_bf16(al[mi], bh[ni], acc[mi][ni], 0, 0, 0);
            }
        __syncthreads();
    }
#pragma unroll
    for (int mi = 0; mi < 4; mi++)
#pragma unroll
        for (int ni = 0; ni < 4; ni++) {
            int col = col0 + wn * 64 + ni * 16 + lrow;
            float bb = bias ? bias[col] : 0.f;
#pragma unroll
            for (int r = 0; r < 4; r++) {
                int row = row0 + wm * 64 + mi * 16 + lq * 4 + r;
                if (row < M) {
                    float v = acc[mi][ni][r] + bb;
                    if (OUT_BF16) Cb[(size_t)row * N + col] = bf16_rne(v);
                    else          C[(size_t)row * N + col] = v;
                }
            }
        }
}

// ---------------------------------------------------------------------------
// proj epilogue: hcur = gemm_out + projW[wid] + projB  (no atomics)
// ---------------------------------------------------------------------------
__global__ void proj_epilogue(const float* __restrict__ res, const float* __restrict__ projW,
                              const float* __restrict__ projB, const int* __restrict__ wid,
                              float* __restrict__ hcur) {
    int n = blockIdx.x, tid = threadIdx.x;
    hcur[(size_t)n * Hh + tid] =
        res[(size_t)n * Hh + tid] + projW[(size_t)wid[n] * Hh + tid] + projB[tid];
}

// ---------------------------------------------------------------------------
// att_dots, one wave per node, bf16 wv
// ---------------------------------------------------------------------------
__global__ __launch_bounds__(256) void att_dots(const unsigned short* __restrict__ wv,
                                                const float* __restrict__ att,
                                                float4* __restrict__ ad,
                                                float4* __restrict__ add) {
    const int wid_g = (blockIdx.x * 256 + threadIdx.x) >> 6;
    const int L = threadIdx.x & 63;
    if (wid_g >= Nn) return;
    const unsigned* wu = (const unsigned*)(wv + (size_t)wid_g * 384);
    float s[3], d[3];
#pragma unroll
    for (int hd = 0; hd < 3; hd++) {
        unsigned u = wu[hd * 64 + L];
        float w0 = bf_lo(u), w1 = bf_hi(u);
        float2 as = *(const float2*)(att + hd * 256 + 2 * L);
        float2 at = *(const float2*)(att + hd * 256 + 128 + 2 * L);
        s[hd] = w0 * as.x + w1 * as.y;
        d[hd] = w0 * at.x + w1 * at.y;
    }
#pragma unroll
    for (int o = 32; o > 0; o >>= 1) {
#pragma unroll
        for (int hd = 0; hd < 3; hd++) {
            s[hd] += __shfl_xor(s[hd], o, 64);
            d[hd] += __shfl_xor(d[hd], o, 64);
        }
    }
    if (L == 0) {
        ad[wid_g]  = make_float4(s[0], s[1], s[2], 0.f);
        add[wid_g] = make_float4(d[0], d[1], d[2], 0.f);
    }
}

// ---------------------------------------------------------------------------
// GAT softmax-attention aggregation, one wave per dst node, bf16 wv gather.
// ---------------------------------------------------------------------------
__global__ __launch_bounds__(256) void gat_aggregate(const unsigned short* __restrict__ wv,
                                                     const float4* __restrict__ ad,
                                                     const float4* __restrict__ add,
                                                     const int* __restrict__ offs,
                                                     const int* __restrict__ csrc,
                                                     float* __restrict__ agg) {
    const int n = (blockIdx.x * 256 + threadIdx.x) >> 6;
    const int L = threadIdx.x & 63;
    if (n >= Nn) return;
    const int start = offs[n];
    const int deg = offs[n + 1] - start;
    float2* o2 = (float2*)(agg + (size_t)n * 384);
    if (deg == 0) {
        float2 z = make_float2(0.f, 0.f);
        o2[L] = z; o2[64 + L] = z; o2[128 + L] = z;
        return;
    }
    const float4 adn = add[n];
    float m0 = -1e30f, m1 = -1e30f, m2 = -1e30f;
    float s0 = 0.f, s1 = 0.f, s2 = 0.f;
    for (int i = L; i < deg; i += 64) {
        int sn = csrc[start + i];
        float4 a4 = ad[sn];
        float a0 = lrelu(a4.x + adn.x);
        float a1 = lrelu(a4.y + adn.y);
        float a2 = lrelu(a4.z + adn.z);
        float nm;
        nm = fmaxf(m0, a0); s0 = s0 * __expf(m0 - nm) + __expf(a0 - nm); m0 = nm;
        nm = fmaxf(m1, a1); s1 = s1 * __expf(m1 - nm) + __expf(a1 - nm); m1 = nm;
        nm = fmaxf(m2, a2); s2 = s2 * __expf(m2 - nm) + __expf(a2 - nm); m2 = nm;
    }
#pragma unroll
    for (int o = 32; o > 0; o >>= 1) {
        float om, os, nm;
        om = __shfl_xor(m0, o, 64); os = __shfl_xor(s0, o, 64);
        nm = fmaxf(m0, om); s0 = s0 * __expf(m0 - nm) + os * __expf(om - nm); m0 = nm;
        om = __shfl_xor(m1, o, 64); os = __shfl_xor(s1, o, 64);
        nm = fmaxf(m1, om); s1 = s1 * __expf(m1 - nm) + os * __expf(om - nm); m1 = nm;
        om = __shfl_xor(m2, o, 64); os = __shfl_xor(s2, o, 64);
        nm = fmaxf(m2, om); s2 = s2 * __expf(m2 - nm) + os * __expf(om - nm); m2 = nm;
    }
    const float i0 = 1.f / s0, i1 = 1.f / s1, i2 = 1.f / s2;
    float2 acc0 = make_float2(0.f, 0.f), acc1 = acc0, acc2 = acc0;
    for (int base = 0; base < deg; base += 64) {
        int cnt = deg - base; if (cnt > 64) cnt = 64;
        int sn = 0; float c0 = 0.f, c1 = 0.f, c2 = 0.f;
        if (L < cnt) {
            sn = csrc[start + base + L];
            float4 a4 = ad[sn];
            c0 = __expf(lrelu(a4.x + adn.x) - m0) * i0;
            c1 = __expf(lrelu(a4.y + adn.y) - m1) * i1;
            c2 = __expf(lrelu(a4.z + adn.z) - m2) * i2;
        }
        for (int j = 0; j < cnt; j++) {
            int    s_n = __shfl(sn, j, 64);
            float  w0  = __shfl(c0, j, 64);
            float  w1  = __shfl(c1, j, 64);
            float  w2  = __shfl(c2, j, 64);
            const unsigned* r2 = (const unsigned*)(wv + (size_t)s_n * 384);
            unsigned u0 = r2[L], u1 = r2[64 + L], u2 = r2[128 + L];
            acc0.x += w0 * bf_lo(u0); acc0.y += w0 * bf_hi(u0);
            acc1.x += w1 * bf_lo(u1); acc1.y += w1 * bf_hi(u1);
            acc2.x += w2 * bf_lo(u2); acc2.y += w2 * bf_hi(u2);
        }
    }
    o2[L] = acc0; o2[64 + L] = acc1; o2[128 + L] = acc2;
}

// ---------------------------------------------------------------------------
// LN epilogue (no atomics, wave-shuffle reductions, 2 barriers)
// ---------------------------------------------------------------------------
__global__ __launch_bounds__(128) void ln_epilogue(const float* __restrict__ res,
                                                   const int* __restrict__ deg,
                                                   const float* __restrict__ gamma,
                                                   const float* __restrict__ beta,
                                                   float* __restrict__ hcur) {
    int n = blockIdx.x, tid = threadIdx.x;
    __shared__ float ws[2][2];
    float x = hcur[(size_t)n * Hh + tid];
    if (deg[n] > 0) x += res[(size_t)n * Hh + tid];
    float s = x;
#pragma unroll
    for (int o = 32; o > 0; o >>= 1) s += __shfl_xor(s, o, 64);
    int wv_ = tid >> 6;
    if ((tid & 63) == 0) ws[0][wv_] = s;
    __syncthreads();
    float mu = (ws[0][0] + ws[0][1]) * (1.f / 128.f);
    float d = x - mu;
    float q = d * d;
#pragma unroll
    for (int o = 32; o > 0; o >>= 1) q += __shfl_xor(q, o, 64);
    if ((tid & 63) == 0) ws[1][wv_] = q;
    __syncthreads();
    float var = (ws[1][0] + ws[1][1]) * (1.f / 128.f);
    float y = d * rsqrtf(var + EPS) * gamma[tid] + beta[tid];
    hcur[(size_t)n * Hh + tid] = fmaxf(y, 0.f);
}

// ---------------------------------------------------------------------------
// GRU layer 0: grid = 400 blocks (b*2+dir), 384 threads (one per gate-unit j).
// reado rows are already per-graph means.
// ---------------------------------------------------------------------------
__global__ __launch_bounds__(384) void gru_layer0(const float* __restrict__ reado,
                                                  const float* __restrict__ WihT,
                                                  const float* __restrict__ WhhT,
                                                  const float* __restrict__ bih,
                                                  const float* __restrict__ bhh,
                                                  float* __restrict__ y0,
                                                  float* __restrict__ fin) {
    const int b = blockIdx.x >> 1, dir = blockIdx.x & 1;
    const int j = threadIdx.x;
    __shared__ float xs[3][128];
    __shared__ float hs[128];
    __shared__ float gil[384], ghl[384];
    if (j < 128) {
#pragma unroll
        for (int t = 0; t < 3; t++)
            xs[t][j] = reado[(size_t)t * Bb * Hh + (size_t)b * Hh + j];
        hs[j] = 0.f;
    }
    __syncthreads();
    const float* Wi = WihT + (size_t)dir * 128 * 384;
    const float* Wh = WhhT + (size_t)dir * 128 * 384;
    float gi[3];
    gi[0] = gi[1] = gi[2] = bih[dir * 384 + j];
    for (int k = 0; k < 128; k++) {
        float w = Wi[(size_t)k * 384 + j];
        gi[0] += w * xs[0][k]; gi[1] += w * xs[1][k]; gi[2] += w * xs[2][k];
    }
    const float bhj = bhh[dir * 384 + j];
    for (int step = 0; step < 3; step++) {
        int t = dir ? 2 - step : step;
        float g = bhj;
        for (int k = 0; k < 128; k++) g += Wh[(size_t)k * 384 + j] * hs[k];
        ghl[j] = g;
        gil[j] = gi[t];
        __syncthreads();
        if (j < 128) {
            float r = sigmoidf(gil[j] + ghl[j]);
            float z = sigmoidf(gil[j + 128] + ghl[j + 128]);
            float nn2 = tanhf(gil[j + 256] + r * ghl[j + 256]);
            float hnew = (1.f - z) * nn2 + z * hs[j];
            hs[j] = hnew;
            y0[(size_t)b * 768 + t * 256 + dir * 128 + j] = hnew;
            if (step == 2) fin[(size_t)dir * Bb * Hh + (size_t)b * Hh + j] = hnew;
        }
        __syncthreads();
    }
}

// GRU layer 1: input y0 [B][3][256]
__global__ __launch_bounds__(384) void gru_layer1(const float* __restrict__ y0,
                                                  const float* __restrict__ WihT,
                                                  const float* __restrict__ WhhT,
                                                  const float* __restrict__ bih,
                                                  const float* __restrict__ bhh,
                                                  float* __restrict__ fin) {
    const int b = blockIdx.x >> 1, dir = blockIdx.x & 1;
    const int j = threadIdx.x;
    __shared__ float xs[3][256];
    __shared__ float hs[128];
    __shared__ float gil[384], ghl[384];
    if (j < 256) {
#pragma unroll
        for (int t = 0; t < 3; t++)
            xs[t][j] = y0[(size_t)b * 768 + t * 256 + j];
    }
    if (j < 128) hs[j] = 0.f;
    __syncthreads();
    const float* Wi = WihT + (size_t)dir * 256 * 384;
    const float* Wh = WhhT + (size_t)dir * 128 * 384;
    float gi[3];
    gi[0] = gi[1] = gi[2] = bih[dir * 384 + j];
    for (int k = 0; k < 256; k++) {
        float w = Wi[(size_t)k * 384 + j];
        gi[0] += w * xs[0][k]; gi[1] += w * xs[1][k]; gi[2] += w * xs[2][k];
    }
    const float bhj = bhh[dir * 384 + j];
    for (int step = 0; step < 3; step++) {
        int t = dir ? 2 - step : step;
        float g = bhj;
        for (int k = 0; k < 128; k++) g += Wh[(size_t)k * 384 + j] * hs[k];
        ghl[j] = g;
        gil[j] = gi[t];
        __syncthreads();
        if (j < 128) {
            float r = sigmoidf(gil[j] + ghl[j]);
            float z = sigmoidf(gil[j + 128] + ghl[j + 128]);
            float nn2 = tanhf(gil[j + 256] + r * ghl[j + 256]);
            float hnew = (1.f - z) * nn2 + z * hs[j];
            hs[j] = hnew;
            if (step == 2) fin[(size_t)(2 + dir) * Bb * Hh + (size_t)b * Hh + j] = hnew;
        }
        __syncthreads();
    }
}

__global__ void final_mean(const float* __restrict__ fin, float* __restrict__ out) {
    int b = blockIdx.x, tid = threadIdx.x;
    const size_t s = (size_t)Bb * Hh;
    out[(size_t)b * Hh + tid] = 0.25f * (fin[b * Hh + tid] + fin[s + b * Hh + tid] +
                                         fin[2 * s + b * Hh + tid] + fin[3 * s + b * Hh + tid]);
}

// ---------------------------------------------------------------------------
extern "C" void kernel_launch(void* const* d_in, const int* in_sizes, int n_in,
                              void* d_out, int out_size, void* d_ws, size_t ws_size,
                              hipStream_t stream) {
    const float* h      = (const float*)d_in[0];
    const int*   wid    = (const int*)d_in[1];
    const int*   src    = (const int*)d_in[2];
    const int*   dst    = (const int*)d_in[3];
    const int*   gid    = (const int*)d_in[4];
    const float* projW  = (const float*)d_in[5];
    const float* projB  = (const float*)d_in[6];
    const float* convWn = (const float*)d_in[7];
    const float* convBn = (const float*)d_in[8];
    const float* convAtt= (const float*)d_in[9];
    const float* convWs = (const float*)d_in[10];
    const float* convB  = (const float*)d_in[11];
    const float* convG  = (const float*)d_in[12];
    const float* convBe = (const float*)d_in[13];
    const float* Wih0   = (const float*)d_in[14];
    const float* Whh0   = (const float*)d_in[15];
    const float* bih0   = (const float*)d_in[16];
    const float* bhh0   = (const float*)d_in[17];
    const float* Wih1   = (const float*)d_in[18];
    const float* Whh1   = (const float*)d_in[19];
    const float* bih1   = (const float*)d_in[20];
    const float* bhh1   = (const float*)d_in[21];
    float* out = (float*)d_out;

    char* p = (char*)d_ws;
    auto alloc_f = [&](size_t n) { float* r = (float*)p; p += n * sizeof(float); return r; };
    auto alloc_i = [&](size_t n) { int* r = (int*)p; p += n * sizeof(int); return r; };
    auto alloc_s = [&](size_t n) { unsigned short* r = (unsigned short*)p; p += n * sizeof(unsigned short); return r; };
    float* hcur  = alloc_f((size_t)Nn * Hh);
    float* agg   = alloc_f((size_t)Nn * 384);
    float* res   = alloc_f((size_t)Nn * Hh);
    float* adbuf = alloc_f((size_t)Nn * 4);
    float* addbuf= alloc_f((size_t)Nn * 4);
    float* reado = alloc_f((size_t)3 * Bb * Hh);
    float* y0    = alloc_f((size_t)Bb * 3 * 256);
    float* fin   = alloc_f((size_t)4 * Bb * Hh);
    float* WihT0 = alloc_f((size_t)2 * 128 * 384);
    float* WhhT0 = alloc_f((size_t)2 * 128 * 384);
    float* WihT1 = alloc_f((size_t)2 * 256 * 384);
    float* WhhT1 = alloc_f((size_t)2 * 128 * 384);
    int* deg  = alloc_i(Nn);
    int* offs = alloc_i(Nn + 1);
    int* cur  = alloc_i(Nn);
    int* csrc = alloc_i(Ee);
    int* goffs = alloc_i(Bb + 1);
    unsigned short* wv = alloc_s((size_t)Nn * 384);   // bf16 wv
    unsigned short* pBth  = alloc_s(128 * 128);
    unsigned short* pBtl  = alloc_s(128 * 128);
    unsigned short* WnTh[2] = { alloc_s(384 * 128), alloc_s(384 * 128) };
    unsigned short* WnTl[2] = { alloc_s(384 * 128), alloc_s(384 * 128) };
    unsigned short* WsTh[2] = { alloc_s(128 * 384), alloc_s(128 * 384) };
    unsigned short* WsTl[2] = { alloc_s(128 * 384), alloc_s(128 * 384) };

    hipMemsetAsync(deg, 0, Nn * sizeof(int), stream);

    hist_dst<<<1250, 256, 0, stream>>>(dst, deg);
    scan_offsets<<<1, 1024, 0, stream>>>(deg, offs, cur);
    fill_csr<<<1250, 256, 0, stream>>>(dst, src, cur, csrc);
    graph_offsets<<<(Nn + 255) / 256, 256, 0, stream>>>(gid, goffs);

    PrepArgs pa;
    pa.projW = projW + (size_t)Vv * Hh; pa.convWn = convWn; pa.convWs = convWs;
    pa.Wih0 = Wih0; pa.Whh0 = Whh0; pa.Wih1 = Wih1; pa.Whh1 = Whh1;
    pa.pBth = pBth; pa.pBtl = pBtl;
    pa.WnTh0 = WnTh[0]; pa.WnTl0 = WnTl[0]; pa.WnTh1 = WnTh[1]; pa.WnTl1 = WnTl[1];
    pa.WsTh0 = WsTh[0]; pa.WsTl0 = WsTl[0]; pa.WsTh1 = WsTh[1]; pa.WsTl1 = WsTl[1];
    pa.WihT0 = WihT0; pa.WhhT0 = WhhT0; pa.WihT1 = WihT1; pa.WhhT1 = WhhT1;
    prep_all<<<(704512 + 255) / 256, 256, 0, stream>>>(pa);

    gemm_mfma_t<false><<<dim3(1, (Nn + 127) / 128), 256, 0, stream>>>(
        h, pBth, pBtl, nullptr, res, nullptr, Nn, 128, 128);
    proj_epilogue<<<Nn, 128, 0, stream>>>(res, projW, projB, wid, hcur);
    readout_mean<<<Bb, 128, 0, stream>>>(hcur, goffs, reado);

    const int nwaveblocks = (Nn * 64 + 255) / 256;   // 5000
    for (int l = 0; l < 2; l++) {
        gemm_mfma_t<true><<<dim3(3, (Nn + 127) / 128), 256, 0, stream>>>(
            hcur, WnTh[l], WnTl[l], convBn + l * 384, nullptr, wv, Nn, 384, 128);
        att_dots<<<nwaveblocks, 256, 0, stream>>>(wv, convAtt + (size_t)l * 3 * 256,
                                                  (float4*)adbuf, (float4*)addbuf);
        gat_aggregate<<<nwaveblocks, 256, 0, stream>>>(wv, (const float4*)adbuf, (const float4*)addbuf,
                                                       offs, csrc, agg);
        gemm_mfma_t<false><<<dim3(1, (Nn + 127) / 128), 256, 0, stream>>>(
            agg, WsTh[l], WsTl[l], convB + l * Hh, res, nullptr, Nn, 128, 384);
        ln_epilogue<<<Nn, 128, 0, stream>>>(res, deg, convG + l * Hh, convBe + l * Hh, hcur);
        readout_mean<<<Bb, 128, 0, stream>>>(hcur, goffs, reado + (size_t)(l + 1) * Bb * Hh);
    }

    gru_layer0<<<2 * Bb, 384, 0, stream>>>(reado, WihT0, WhhT0, bih0, bhh0, y0, fin);
    gru_layer1<<<2 * Bb, 384, 0, stream>>>(y0, WihT1, WhhT1, bih1, bhh1, fin);
    final_mean<<<Bb, 128, 0, stream>>>(fin, out);
}

// Round 7
// 555.593 us; speedup vs baseline: 1.0680x; 1.0680x over previous
//
#include <hip/hip_runtime.h>
#include <cstddef>

// Problem constants (from reference)
static constexpr int Nn    = 20000;
static constexpr int Ee    = 320000;
static constexpr int Vv    = 100;
static constexpr int Hh    = 128;
static constexpr int HEADS = 3;
static constexpr int Bb    = 200;
static constexpr float NEG = 0.2f;
static constexpr float EPS = 1e-5f;

typedef short bf16x8 __attribute__((ext_vector_type(8)));
typedef float f32x4  __attribute__((ext_vector_type(4)));

__device__ inline unsigned short bf16_rne(float x) {
    unsigned u = __builtin_bit_cast(unsigned, x);
    u += 0x7FFFu + ((u >> 16) & 1u);
    return (unsigned short)(u >> 16);
}
__device__ inline float bf16_f(unsigned short h) {
    unsigned u = ((unsigned)h) << 16;
    return __builtin_bit_cast(float, u);
}
__device__ inline float bf_lo(unsigned u) { return __builtin_bit_cast(float, u << 16); }
__device__ inline float bf_hi(unsigned u) { return __builtin_bit_cast(float, u & 0xFFFF0000u); }
__device__ inline float lrelu(float a) { return a >= 0.f ? a : NEG * a; }
__device__ inline float sigmoidf(float x) { return 1.f / (1.f + __expf(-x)); }

// ---------------------------------------------------------------------------
// CSR build
// ---------------------------------------------------------------------------
__global__ void hist_dst(const int* __restrict__ dst, int* __restrict__ deg) {
    for (int i = blockIdx.x * blockDim.x + threadIdx.x; i < Ee; i += gridDim.x * blockDim.x)
        atomicAdd(&deg[dst[i]], 1);
}

__global__ __launch_bounds__(1024) void scan_offsets(const int* __restrict__ deg,
                                                     int* __restrict__ offs,
                                                     int* __restrict__ cur) {
    __shared__ int sums[1024];
    const int tid = threadIdx.x;
    const int per = (Nn + 1023) >> 10;
    int begin = tid * per;
    int end = begin + per; if (end > Nn) end = Nn;
    if (begin > Nn) begin = Nn;
    int s = 0;
    for (int i = begin; i < end; i++) s += deg[i];
    sums[tid] = s;
    __syncthreads();
    for (int off = 1; off < 1024; off <<= 1) {
        int v = (tid >= off) ? sums[tid - off] : 0;
        __syncthreads();
        sums[tid] += v;
        __syncthreads();
    }
    int run = sums[tid] - s;
    for (int i = begin; i < end; i++) {
        offs[i] = run; cur[i] = run;
        run += deg[i];
    }
    if (end == Nn) offs[Nn] = run;
}

__global__ void fill_csr(const int* __restrict__ dst, const int* __restrict__ src,
                         int* __restrict__ cur, int* __restrict__ csrc) {
    for (int i = blockIdx.x * blockDim.x + threadIdx.x; i < Ee; i += gridDim.x * blockDim.x) {
        int p = atomicAdd(&cur[dst[i]], 1);
        csrc[p] = src[i];
    }
}

// Per-graph mean over contiguous node range (gid sorted).
__global__ __launch_bounds__(128) void readout_mean(const float* __restrict__ hcur,
                                                    const int* __restrict__ goffs,
                                                    float* __restrict__ reado_t) {
    const int b = blockIdx.x, j = threadIdx.x;
    const int s = goffs[b], e = goffs[b + 1];
    float acc = 0.f;
    for (int n = s; n < e; n++) acc += hcur[(size_t)n * Hh + j];
    float inv = (e > s) ? 1.f / (float)(e - s) : 0.f;
    reado_t[(size_t)b * Hh + j] = acc * inv;
}

// ---------------------------------------------------------------------------
// Fused weight prep + graph_offsets (one launch)
// ---------------------------------------------------------------------------
struct PrepArgs {
    const float *projW, *convWn, *convWs, *Wih0, *Whh0, *Wih1, *Whh1;
    const int* gid;
    unsigned short *pBth, *pBtl;
    unsigned short *WnTh0, *WnTl0, *WnTh1, *WnTl1;
    unsigned short *WsTh0, *WsTl0, *WsTh1, *WsTl1;
    float *WihT0, *WhhT0, *WihT1, *WhhT1;
    int* goffs;
};

__device__ inline void wsplit(const float* B, int K, int N, int idx,
                              unsigned short* Bth, unsigned short* Btl) {
    int k = idx / N, n = idx - k * N;
    float v = B[idx];
    unsigned short h = bf16_rne(v);
    unsigned short l = bf16_rne(v - bf16_f(h));
    Bth[(size_t)n * K + k] = h;
    Btl[(size_t)n * K + k] = l;
}
__device__ inline void gruT(const float* W, int K, int idx, float* WT) {
    int d = idx / (384 * K);
    int r = idx - d * 384 * K;
    int j = r / K, k = r - j * K;
    WT[(size_t)d * K * 384 + (size_t)k * 384 + j] = W[idx];
}

__global__ void prep_all(PrepArgs a) {
    int i = blockIdx.x * blockDim.x + threadIdx.x;
    if (i < 16384)  { wsplit(a.projW, 128, 128, i, a.pBth, a.pBtl); return; }   i -= 16384;
    if (i < 49152)  { wsplit(a.convWn, 128, 384, i, a.WnTh0, a.WnTl0); return; } i -= 49152;
    if (i < 49152)  { wsplit(a.convWn + 49152, 128, 384, i, a.WnTh1, a.WnTl1); return; } i -= 49152;
    if (i < 49152)  { wsplit(a.convWs, 384, 128, i, a.WsTh0, a.WsTl0); return; } i -= 49152;
    if (i < 49152)  { wsplit(a.convWs + 49152, 384, 128, i, a.WsTh1, a.WsTl1); return; } i -= 49152;
    if (i < 98304)  { gruT(a.Wih0, 128, i, a.WihT0); return; }  i -= 98304;
    if (i < 98304)  { gruT(a.Whh0, 128, i, a.WhhT0); return; }  i -= 98304;
    if (i < 196608) { gruT(a.Wih1, 256, i, a.WihT1); return; }  i -= 196608;
    if (i < 98304)  { gruT(a.Whh1, 128, i, a.WhhT1); return; }  i -= 98304;
    if (i < Nn) {
        int g = a.gid[i];
        if (i == 0) { for (int b = 0; b <= g; b++) a.goffs[b] = 0; }
        else { int pg = a.gid[i - 1]; for (int b = pg + 1; b <= g; b++) a.goffs[b] = i; }
        if (i == Nn - 1) { for (int b = g + 1; b <= Bb; b++) a.goffs[b] = Nn; }
    }
}

// ---------------------------------------------------------------------------
// Split-bf16 MFMA GEMM with fused epilogues.
// BM=128, BN=128, BK=32; 256 threads (2x2 waves); wave tile 64x64.
// MODE 0: proj  (N=K=128): out hcur = acc + bias + projW[wid[row]]
// MODE 1: Wn+att (N=384):  out wv bf16 = acc+bias; per-head att dots -> ad/add
// MODE 2: Ws+LN (N=128, K=384): x = hcur_old + (deg>0 ? acc+bias : 0);
//                               LayerNorm, ReLU -> hcur
// ---------------------------------------------------------------------------
struct GArgs {
    const float* A; const unsigned short* Bth; const unsigned short* Btl;
    const float* bias; int M, N, K;
    const int* wid; const float* projW;                 // MODE 0
    unsigned short* Cb; float* adf; float* addf; const float* att;  // MODE 1
    const int* deg; const float* gamma; const float* beta;          // MODE 2
    float* hcur;                                        // MODE 0/2 out, MODE 2 in
};

template <int MODE>
__global__ __launch_bounds__(256) void gemm_fused(GArgs a) {
    __shared__ unsigned short As_hi[128][40];
    __shared__ unsigned short As_lo[128][40];
    __shared__ unsigned short Bs_hi[128][40];
    __shared__ unsigned short Bs_lo[128][40];
    const int tid  = threadIdx.x;
    const int row0 = blockIdx.y * 128;
    const int col0 = blockIdx.x * 128;
    const int w    = tid >> 6;
    const int wm   = w >> 1;
    const int wn   = w & 1;
    const int L    = tid & 63;
    const int lrow = L & 15;
    const int lq   = L >> 4;
    const int M = a.M, N = a.N, K = a.K;

    f32x4 acc[4][4];
#pragma unroll
    for (int i = 0; i < 4; i++)
#pragma unroll
        for (int j = 0; j < 4; j++) acc[i][j] = (f32x4){0.f, 0.f, 0.f, 0.f};

    for (int kb = 0; kb < K; kb += 32) {
#pragma unroll
        for (int it = 0; it < 4; it++) {
            int idx = tid + it * 256;
            int m  = idx >> 3;
            int kq = (idx & 7) * 4;
            int gr = row0 + m;
            float4 v = make_float4(0.f, 0.f, 0.f, 0.f);
            if (gr < M) v = *(const float4*)(a.A + (size_t)gr * K + kb + kq);
            unsigned short h0 = bf16_rne(v.x), h1 = bf16_rne(v.y),
                           h2 = bf16_rne(v.z), h3 = bf16_rne(v.w);
            short4 hi4 = make_short4((short)h0, (short)h1, (short)h2, (short)h3);
            short4 lo4 = make_short4((short)bf16_rne(v.x - bf16_f(h0)),
                                     (short)bf16_rne(v.y - bf16_f(h1)),
                                     (short)bf16_rne(v.z - bf16_f(h2)),
                                     (short)bf16_rne(v.w - bf16_f(h3)));
            *(short4*)&As_hi[m][kq] = hi4;
            *(short4*)&As_lo[m][kq] = lo4;
        }
        {
            int n  = tid >> 1;
            int kh = (tid & 1) * 16;
            const unsigned short* sh = a.Bth + (size_t)(col0 + n) * K + kb + kh;
            const unsigned short* sl = a.Btl + (size_t)(col0 + n) * K + kb + kh;
            *(float4*)&Bs_hi[n][kh]     = *(const float4*)sh;
            *(float4*)&Bs_hi[n][kh + 8] = *(const float4*)(sh + 8);
            *(float4*)&Bs_lo[n][kh]     = *(const float4*)sl;
            *(float4*)&Bs_lo[n][kh + 8] = *(const float4*)(sl + 8);
        }
        __syncthreads();
        bf16x8 ah[4], al[4], bh[4], bl[4];
#pragma unroll
        for (int mi = 0; mi < 4; mi++) {
            int r = wm * 64 + mi * 16 + lrow;
            ah[mi] = *(const bf16x8*)&As_hi[r][lq * 8];
            al[mi] = *(const bf16x8*)&As_lo[r][lq * 8];
        }
#pragma unroll
        for (int ni = 0; ni < 4; ni++) {
            int r = wn * 64 + ni * 16 + lrow;
            bh[ni] = *(const bf16x8*)&Bs_hi[r][lq * 8];
            bl[ni] = *(const bf16x8*)&Bs_lo[r][lq * 8];
        }
#pragma unroll
        for (int mi = 0; mi < 4; mi++)
#pragma unroll
            for (int ni = 0; ni < 4; ni++) {
                acc[mi][ni] = __builtin_amdgcn_mfma_f32_16x16x32_bf16(ah[mi], bh[ni], acc[mi][ni], 0, 0, 0);
                acc[mi][ni] = __builtin_amdgcn_mfma_f32_16x16x32_bf16(ah[mi], bl[ni], acc[mi][ni], 0, 0, 0);
                acc[mi][ni] = __builtin_amdgcn_mfma_f32_16x16x32_bf16(al[mi], bh[ni], acc[mi][ni], 0, 0, 0);
            }
        __syncthreads();
    }

    // ---- add bias into acc (bias along cols) ----
    float b4[4];
#pragma unroll
    for (int ni = 0; ni < 4; ni++) b4[ni] = a.bias ? a.bias[col0 + wn * 64 + ni * 16 + lrow] : 0.f;
#pragma unroll
    for (int mi = 0; mi < 4; mi++)
#pragma unroll
        for (int ni = 0; ni < 4; ni++)
#pragma unroll
            for (int r = 0; r < 4; r++) acc[mi][ni][r] += b4[ni];

    if constexpr (MODE == 0) {
        // proj: hcur = acc + projW[wid[row]] (bias already in acc)
#pragma unroll
        for (int mi = 0; mi < 4; mi++)
#pragma unroll
            for (int r = 0; r < 4; r++) {
                int row = row0 + wm * 64 + mi * 16 + lq * 4 + r;
                if (row < M) {
                    int wi = a.wid[row];
#pragma unroll
                    for (int ni = 0; ni < 4; ni++) {
                        int c = wn * 64 + ni * 16 + lrow;
                        a.hcur[(size_t)row * 128 + c] = acc[mi][ni][r] + a.projW[(size_t)wi * 128 + c];
                    }
                }
            }
    }

    if constexpr (MODE == 1) {
        // write bf16 wv
#pragma unroll
        for (int mi = 0; mi < 4; mi++)
#pragma unroll
            for (int ni = 0; ni < 4; ni++) {
                int col = col0 + wn * 64 + ni * 16 + lrow;
#pragma unroll
                for (int r = 0; r < 4; r++) {
                    int row = row0 + wm * 64 + mi * 16 + lq * 4 + r;
                    if (row < M) a.Cb[(size_t)row * N + col] = bf16_rne(acc[mi][ni][r]);
                }
            }
        // att dots for this head (blockIdx.x = head)
        const int h = blockIdx.x;
        const float* attS = a.att + h * 256;
        const float* attD = attS + 128;
        __shared__ float sred[128][2], dred[128][2];
        float as4[4], ad4[4];
#pragma unroll
        for (int ni = 0; ni < 4; ni++) {
            int cl = wn * 64 + ni * 16 + lrow;
            as4[ni] = attS[cl]; ad4[ni] = attD[cl];
        }
#pragma unroll
        for (int mi = 0; mi < 4; mi++)
#pragma unroll
            for (int r = 0; r < 4; r++) {
                float ps = 0.f, pd = 0.f;
#pragma unroll
                for (int ni = 0; ni < 4; ni++) {
                    ps += acc[mi][ni][r] * as4[ni];
                    pd += acc[mi][ni][r] * ad4[ni];
                }
#pragma unroll
                for (int o = 1; o < 16; o <<= 1) {
                    ps += __shfl_xor(ps, o, 64);
                    pd += __shfl_xor(pd, o, 64);
                }
                if (lrow == 0) {
                    int lr = wm * 64 + mi * 16 + lq * 4 + r;
                    sred[lr][wn] = ps; dred[lr][wn] = pd;
                }
            }
        __syncthreads();
        if (tid < 128) {
            int row = row0 + tid;
            if (row < M) {
                a.adf[(size_t)row * 4 + h]  = sred[tid][0] + sred[tid][1];
                a.addf[(size_t)row * 4 + h] = dred[tid][0] + dred[tid][1];
            }
        }
    }

    if constexpr (MODE == 2) {
        // x = hcur_old + (deg>0 ? acc : 0); LayerNorm; ReLU -> hcur
        __shared__ float red1[128][2], red2[128][2];
        float g4[4], be4[4];
#pragma unroll
        for (int ni = 0; ni < 4; ni++) {
            int c = wn * 64 + ni * 16 + lrow;
            g4[ni] = a.gamma[c]; be4[ni] = a.beta[c];
        }
#pragma unroll
        for (int mi = 0; mi < 4; mi++)
#pragma unroll
            for (int r = 0; r < 4; r++) {
                int row = row0 + wm * 64 + mi * 16 + lq * 4 + r;
                int dg = (row < M) ? a.deg[row] : 1;
#pragma unroll
                for (int ni = 0; ni < 4; ni++) {
                    int c = wn * 64 + ni * 16 + lrow;
                    float hold = (row < M) ? a.hcur[(size_t)row * 128 + c] : 0.f;
                    float v = (dg > 0) ? acc[mi][ni][r] : 0.f;
                    acc[mi][ni][r] = hold + v;
                }
            }
        // row sums
#pragma unroll
        for (int mi = 0; mi < 4; mi++)
#pragma unroll
            for (int r = 0; r < 4; r++) {
                float ps = acc[mi][0][r] + acc[mi][1][r] + acc[mi][2][r] + acc[mi][3][r];
#pragma unroll
                for (int o = 1; o < 16; o <<= 1) ps += __shfl_xor(ps, o, 64);
                if (lrow == 0) red1[wm * 64 + mi * 16 + lq * 4 + r][wn] = ps;
            }
        __syncthreads();
#pragma unroll
        for (int mi = 0; mi < 4; mi++)
#pragma unroll
            for (int r = 0; r < 4; r++) {
                int lr = wm * 64 + mi * 16 + lq * 4 + r;
                float mu = (red1[lr][0] + red1[lr][1]) * (1.f / 128.f);
                float qs = 0.f;
#pragma unroll
                for (int ni = 0; ni < 4; ni++) {
                    float dx = acc[mi][ni][r] - mu;
                    qs += dx * dx;
                }
#pragma unroll
                for (int o = 1; o < 16; o <<= 1) qs += __shfl_xor(qs, o, 64);
                if (lrow == 0) red2[lr][wn] = qs;
            }
        __syncthreads();
#pragma unroll
        for (int mi = 0; mi < 4; mi++)
#pragma unroll
            for (int r = 0; r < 4; r++) {
                int lr = wm * 64 + mi * 16 + lq * 4 + r;
                int row = row0 + lr;
                if (row >= M) continue;
                float mu = (red1[lr][0] + red1[lr][1]) * (1.f / 128.f);
                float var = (red2[lr][0] + red2[lr][1]) * (1.f / 128.f);
                float rs = rsqrtf(var + EPS);
#pragma unroll
                for (int ni = 0; ni < 4; ni++) {
                    int c = wn * 64 + ni * 16 + lrow;
                    float y = (acc[mi][ni][r] - mu) * rs * g4[ni] + be4[ni];
                    a.hcur[(size_t)row * 128 + c] = fmaxf(y, 0.f);
                }
            }
    }
}

// ---------------------------------------------------------------------------
// GAT softmax-attention aggregation, one wave per dst node, bf16 wv gather.
// ---------------------------------------------------------------------------
__global__ __launch_bounds__(256) void gat_aggregate(const unsigned short* __restrict__ wv,
                                                     const float4* __restrict__ ad,
                                                     const float4* __restrict__ add,
                                                     const int* __restrict__ offs,
                                                     const int* __restrict__ csrc,
                                                     float* __restrict__ agg) {
    const int n = (blockIdx.x * 256 + threadIdx.x) >> 6;
    const int L = threadIdx.x & 63;
    if (n >= Nn) return;
    const int start = offs[n];
    const int deg = offs[n + 1] - start;
    float2* o2 = (float2*)(agg + (size_t)n * 384);
    if (deg == 0) {
        float2 z = make_float2(0.f, 0.f);
        o2[L] = z; o2[64 + L] = z; o2[128 + L] = z;
        return;
    }
    const float4 adn = add[n];
    float m0 = -1e30f, m1 = -1e30f, m2 = -1e30f;
    float s0 = 0.f, s1 = 0.f, s2 = 0.f;
    for (int i = L; i < deg; i += 64) {
        int sn = csrc[start + i];
        float4 a4 = ad[sn];
        float a0 = lrelu(a4.x + adn.x);
        float a1 = lrelu(a4.y + adn.y);
        float a2 = lrelu(a4.z + adn.z);
        float nm;
        nm = fmaxf(m0, a0); s0 = s0 * __expf(m0 - nm) + __expf(a0 - nm); m0 = nm;
        nm = fmaxf(m1, a1); s1 = s1 * __expf(m1 - nm) + __expf(a1 - nm); m1 = nm;
        nm = fmaxf(m2, a2); s2 = s2 * __expf(m2 - nm) + __expf(a2 - nm); m2 = nm;
    }
#pragma unroll
    for (int o = 32; o > 0; o >>= 1) {
        float om, os, nm;
        om = __shfl_xor(m0, o, 64); os = __shfl_xor(s0, o, 64);
        nm = fmaxf(m0, om); s0 = s0 * __expf(m0 - nm) + os * __expf(om - nm); m0 = nm;
        om = __shfl_xor(m1, o, 64); os = __shfl_xor(s1, o, 64);
        nm = fmaxf(m1, om); s1 = s1 * __expf(m1 - nm) + os * __expf(om - nm); m1 = nm;
        om = __shfl_xor(m2, o, 64); os = __shfl_xor(s2, o, 64);
        nm = fmaxf(m2, om); s2 = s2 * __expf(m2 - nm) + os * __expf(om - nm); m2 = nm;
    }
    const float i0 = 1.f / s0, i1 = 1.f / s1, i2 = 1.f / s2;
    float2 acc0 = make_float2(0.f, 0.f), acc1 = acc0, acc2 = acc0;
    for (int base = 0; base < deg; base += 64) {
        int cnt = deg - base; if (cnt > 64) cnt = 64;
        int sn = 0; float c0 = 0.f, c1 = 0.f, c2 = 0.f;
        if (L < cnt) {
            sn = csrc[start + base + L];
            float4 a4 = ad[sn];
            c0 = __expf(lrelu(a4.x + adn.x) - m0) * i0;
            c1 = __expf(lrelu(a4.y + adn.y) - m1) * i1;
            c2 = __expf(lrelu(a4.z + adn.z) - m2) * i2;
        }
        for (int j = 0; j < cnt; j++) {
            int    s_n = __shfl(sn, j, 64);
            float  w0  = __shfl(c0, j, 64);
            float  w1  = __shfl(c1, j, 64);
            float  w2  = __shfl(c2, j, 64);
            const unsigned* r2 = (const unsigned*)(wv + (size_t)s_n * 384);
            unsigned u0 = r2[L], u1 = r2[64 + L], u2 = r2[128 + L];
            acc0.x += w0 * bf_lo(u0); acc0.y += w0 * bf_hi(u0);
            acc1.x += w1 * bf_lo(u1); acc1.y += w1 * bf_hi(u1);
            acc2.x += w2 * bf_lo(u2); acc2.y += w2 * bf_hi(u2);
        }
    }
    o2[L] = acc0; o2[64 + L] = acc1; o2[128 + L] = acc2;
}

// ---------------------------------------------------------------------------
// Full GRU stack: one block per batch element, 768 threads (2 dirs x 384).
// ---------------------------------------------------------------------------
__global__ __launch_bounds__(768) void gru_all(const float* __restrict__ reado,
                                               const float* __restrict__ WihT0,
                                               const float* __restrict__ WhhT0,
                                               const float* __restrict__ bih0,
                                               const float* __restrict__ bhh0,
                                               const float* __restrict__ WihT1,
                                               const float* __restrict__ WhhT1,
                                               const float* __restrict__ bih1,
                                               const float* __restrict__ bhh1,
                                               float* __restrict__ out) {
    const int b = blockIdx.x;
    const int tid = threadIdx.x;
    const int dir = tid / 384;
    const int j = tid - dir * 384;
    __shared__ float xs[3][128];
    __shared__ float y0s[3][256];
    __shared__ float hs[2][128];
    __shared__ float gil[2][384], ghl[2][384];
    __shared__ float fin01[2][128];
    if (tid < 128) {
#pragma unroll
        for (int t = 0; t < 3; t++)
            xs[t][tid] = reado[(size_t)t * Bb * Hh + (size_t)b * Hh + tid];
    }
    if (j < 128) hs[dir][j] = 0.f;
    __syncthreads();
    // ---- layer 0 ----
    {
        const float* Wi = WihT0 + (size_t)dir * 128 * 384;
        const float* Wh = WhhT0 + (size_t)dir * 128 * 384;
        float gi[3];
        gi[0] = gi[1] = gi[2] = bih0[dir * 384 + j];
        for (int k = 0; k < 128; k++) {
            float w = Wi[(size_t)k * 384 + j];
            gi[0] += w * xs[0][k]; gi[1] += w * xs[1][k]; gi[2] += w * xs[2][k];
        }
        const float bhj = bhh0[dir * 384 + j];
        for (int step = 0; step < 3; step++) {
            int t = dir ? 2 - step : step;
            float g = bhj;
            for (int k = 0; k < 128; k++) g += Wh[(size_t)k * 384 + j] * hs[dir][k];
            ghl[dir][j] = g;
            gil[dir][j] = gi[t];
            __syncthreads();
            if (j < 128) {
                float r = sigmoidf(gil[dir][j] + ghl[dir][j]);
                float z = sigmoidf(gil[dir][j + 128] + ghl[dir][j + 128]);
                float nn2 = tanhf(gil[dir][j + 256] + r * ghl[dir][j + 256]);
                float hnew = (1.f - z) * nn2 + z * hs[dir][j];
                hs[dir][j] = hnew;
                y0s[t][dir * 128 + j] = hnew;
                if (step == 2) fin01[dir][j] = hnew;
            }
            __syncthreads();
        }
    }
    // ---- layer 1 ----
    if (j < 128) hs[dir][j] = 0.f;
    {
        const float* Wi = WihT1 + (size_t)dir * 256 * 384;
        const float* Wh = WhhT1 + (size_t)dir * 128 * 384;
        float gi[3];
        gi[0] = gi[1] = gi[2] = bih1[dir * 384 + j];
        for (int k = 0; k < 256; k++) {
            float w = Wi[(size_t)k * 384 + j];
            gi[0] += w * y0s[0][k]; gi[1] += w * y0s[1][k]; gi[2] += w * y0s[2][k];
        }
        const float bhj = bhh1[dir * 384 + j];
        __syncthreads();
        for (int step = 0; step < 3; step++) {
            int t = dir ? 2 - step : step;
            float g = bhj;
            for (int k = 0; k < 128; k++) g += Wh[(size_t)k * 384 + j] * hs[dir][k];
            ghl[dir][j] = g;
            gil[dir][j] = gi[t];
            __syncthreads();
            if (j < 128) {
                float r = sigmoidf(gil[dir][j] + ghl[dir][j]);
                float z = sigmoidf(gil[dir][j + 128] + ghl[dir][j + 128]);
                float nn2 = tanhf(gil[dir][j + 256] + r * ghl[dir][j + 256]);
                float hnew = (1.f - z) * nn2 + z * hs[dir][j];
                hs[dir][j] = hnew;
                if (step == 2) xs[dir][j] = hnew;   // reuse xs as fin23
            }
            __syncthreads();
        }
    }
    if (tid < 128)
        out[(size_t)b * Hh + tid] = 0.25f * (fin01[0][tid] + fin01[1][tid] +
                                             xs[0][tid] + xs[1][tid]);
}

// ---------------------------------------------------------------------------
extern "C" void kernel_launch(void* const* d_in, const int* in_sizes, int n_in,
                              void* d_out, int out_size, void* d_ws, size_t ws_size,
                              hipStream_t stream) {
    const float* h      = (const float*)d_in[0];
    const int*   wid    = (const int*)d_in[1];
    const int*   src    = (const int*)d_in[2];
    const int*   dst    = (const int*)d_in[3];
    const int*   gid    = (const int*)d_in[4];
    const float* projW  = (const float*)d_in[5];
    const float* projB  = (const float*)d_in[6];
    const float* convWn = (const float*)d_in[7];
    const float* convBn = (const float*)d_in[8];
    const float* convAtt= (const float*)d_in[9];
    const float* convWs = (const float*)d_in[10];
    const float* convB  = (const float*)d_in[11];
    const float* convG  = (const float*)d_in[12];
    const float* convBe = (const float*)d_in[13];
    const float* Wih0   = (const float*)d_in[14];
    const float* Whh0   = (const float*)d_in[15];
    const float* bih0   = (const float*)d_in[16];
    const float* bhh0   = (const float*)d_in[17];
    const float* Wih1   = (const float*)d_in[18];
    const float* Whh1   = (const float*)d_in[19];
    const float* bih1   = (const float*)d_in[20];
    const float* bhh1   = (const float*)d_in[21];
    float* out = (float*)d_out;

    char* p = (char*)d_ws;
    auto alloc_f = [&](size_t n) { float* r = (float*)p; p += n * sizeof(float); return r; };
    auto alloc_i = [&](size_t n) { int* r = (int*)p; p += n * sizeof(int); return r; };
    auto alloc_s = [&](size_t n) { unsigned short* r = (unsigned short*)p; p += n * sizeof(unsigned short); return r; };
    float* hcur  = alloc_f((size_t)Nn * Hh);
    float* agg   = alloc_f((size_t)Nn * 384);
    float* adbuf = alloc_f((size_t)Nn * 4);
    float* addbuf= alloc_f((size_t)Nn * 4);
    float* reado = alloc_f((size_t)3 * Bb * Hh);
    float* WihT0 = alloc_f((size_t)2 * 128 * 384);
    float* WhhT0 = alloc_f((size_t)2 * 128 * 384);
    float* WihT1 = alloc_f((size_t)2 * 256 * 384);
    float* WhhT1 = alloc_f((size_t)2 * 128 * 384);
    int* deg  = alloc_i(Nn);
    int* offs = alloc_i(Nn + 1);
    int* cur  = alloc_i(Nn);
    int* csrc = alloc_i(Ee);
    int* goffs = alloc_i(Bb + 1);
    unsigned short* wv = alloc_s((size_t)Nn * 384);
    unsigned short* pBth  = alloc_s(128 * 128);
    unsigned short* pBtl  = alloc_s(128 * 128);
    unsigned short* WnTh[2] = { alloc_s(384 * 128), alloc_s(384 * 128) };
    unsigned short* WnTl[2] = { alloc_s(384 * 128), alloc_s(384 * 128) };
    unsigned short* WsTh[2] = { alloc_s(128 * 384), alloc_s(128 * 384) };
    unsigned short* WsTl[2] = { alloc_s(128 * 384), alloc_s(128 * 384) };

    hipMemsetAsync(deg, 0, Nn * sizeof(int), stream);

    hist_dst<<<1250, 256, 0, stream>>>(dst, deg);
    scan_offsets<<<1, 1024, 0, stream>>>(deg, offs, cur);
    fill_csr<<<1250, 256, 0, stream>>>(dst, src, cur, csrc);

    PrepArgs pa;
    pa.projW = projW + (size_t)Vv * Hh; pa.convWn = convWn; pa.convWs = convWs;
    pa.Wih0 = Wih0; pa.Whh0 = Whh0; pa.Wih1 = Wih1; pa.Whh1 = Whh1;
    pa.gid = gid;
    pa.pBth = pBth; pa.pBtl = pBtl;
    pa.WnTh0 = WnTh[0]; pa.WnTl0 = WnTl[0]; pa.WnTh1 = WnTh[1]; pa.WnTl1 = WnTl[1];
    pa.WsTh0 = WsTh[0]; pa.WsTl0 = WsTl[0]; pa.WsTh1 = WsTh[1]; pa.WsTl1 = WsTl[1];
    pa.WihT0 = WihT0; pa.WhhT0 = WhhT0; pa.WihT1 = WihT1; pa.WhhT1 = WhhT1;
    pa.goffs = goffs;
    prep_all<<<(724512 + 255) / 256, 256, 0, stream>>>(pa);

    const int rowblocks = (Nn + 127) / 128;   // 157

    // projection (fused epilogue)
    {
        GArgs g = {};
        g.A = h; g.Bth = pBth; g.Btl = pBtl; g.bias = projB;
        g.M = Nn; g.N = 128; g.K = 128;
        g.wid = wid; g.projW = projW; g.hcur = hcur;
        gemm_fused<0><<<dim3(1, rowblocks), 256, 0, stream>>>(g);
    }
    readout_mean<<<Bb, 128, 0, stream>>>(hcur, goffs, reado);

    const int nwaveblocks = (Nn * 64 + 255) / 256;   // 5000
    for (int l = 0; l < 2; l++) {
        {
            GArgs g = {};
            g.A = hcur; g.Bth = WnTh[l]; g.Btl = WnTl[l]; g.bias = convBn + l * 384;
            g.M = Nn; g.N = 384; g.K = 128;
            g.Cb = wv; g.adf = adbuf; g.addf = addbuf;
            g.att = convAtt + (size_t)l * 3 * 256;
            gemm_fused<1><<<dim3(3, rowblocks), 256, 0, stream>>>(g);
        }
        gat_aggregate<<<nwaveblocks, 256, 0, stream>>>(wv, (const float4*)adbuf, (const float4*)addbuf,
                                                       offs, csrc, agg);
        {
            GArgs g = {};
            g.A = agg; g.Bth = WsTh[l]; g.Btl = WsTl[l]; g.bias = convB + l * Hh;
            g.M = Nn; g.N = 128; g.K = 384;
            g.deg = deg; g.gamma = convG + l * Hh; g.beta = convBe + l * Hh;
            g.hcur = hcur;
            gemm_fused<2><<<dim3(1, rowblocks), 256, 0, stream>>>(g);
        }
        readout_mean<<<Bb, 128, 0, stream>>>(hcur, goffs, reado + (size_t)(l + 1) * Bb * Hh);
    }

    gru_all<<<Bb, 768, 0, stream>>>(reado, WihT0, WhhT0, bih0, bhh0,
                                    WihT1, WhhT1, bih1, bhh1, out);
}

// Round 8
// 415.502 us; speedup vs baseline: 1.4281x; 1.3372x over previous
//
#include <hip/hip_runtime.h>
#include <cstddef>

// Problem constants (from reference)
static constexpr int Nn    = 20000;
static constexpr int Ee    = 320000;
static constexpr int Vv    = 100;
static constexpr int Hh    = 128;
static constexpr int HEADS = 3;
static constexpr int Bb    = 200;
static constexpr float NEG = 0.2f;
static constexpr float EPS = 1e-5f;

typedef short bf16x8 __attribute__((ext_vector_type(8)));
typedef float f32x4  __attribute__((ext_vector_type(4)));

__device__ inline unsigned short bf16_rne(float x) {
    unsigned u = __builtin_bit_cast(unsigned, x);
    u += 0x7FFFu + ((u >> 16) & 1u);
    return (unsigned short)(u >> 16);
}
__device__ inline float bf16_f(unsigned short h) {
    unsigned u = ((unsigned)h) << 16;
    return __builtin_bit_cast(float, u);
}
__device__ inline float bf_lo(unsigned u) { return __builtin_bit_cast(float, u << 16); }
__device__ inline float bf_hi(unsigned u) { return __builtin_bit_cast(float, u & 0xFFFF0000u); }
__device__ inline float lrelu(float a) { return a >= 0.f ? a : NEG * a; }
__device__ inline float sigmoidf(float x) { return 1.f / (1.f + __expf(-x)); }

// ---------------------------------------------------------------------------
// CSR build
// ---------------------------------------------------------------------------
__global__ void hist_dst(const int* __restrict__ dst, int* __restrict__ deg) {
    for (int i = blockIdx.x * blockDim.x + threadIdx.x; i < Ee; i += gridDim.x * blockDim.x)
        atomicAdd(&deg[dst[i]], 1);
}

__global__ __launch_bounds__(1024) void scan_offsets(const int* __restrict__ deg,
                                                     int* __restrict__ offs,
                                                     int* __restrict__ cur) {
    __shared__ int sums[1024];
    const int tid = threadIdx.x;
    const int per = (Nn + 1023) >> 10;
    int begin = tid * per;
    int end = begin + per; if (end > Nn) end = Nn;
    if (begin > Nn) begin = Nn;
    int s = 0;
    for (int i = begin; i < end; i++) s += deg[i];
    sums[tid] = s;
    __syncthreads();
    for (int off = 1; off < 1024; off <<= 1) {
        int v = (tid >= off) ? sums[tid - off] : 0;
        __syncthreads();
        sums[tid] += v;
        __syncthreads();
    }
    int run = sums[tid] - s;
    for (int i = begin; i < end; i++) {
        offs[i] = run; cur[i] = run;
        run += deg[i];
    }
    if (end == Nn) offs[Nn] = run;
}

__global__ void fill_csr(const int* __restrict__ dst, const int* __restrict__ src,
                         int* __restrict__ cur, int* __restrict__ csrc) {
    for (int i = blockIdx.x * blockDim.x + threadIdx.x; i < Ee; i += gridDim.x * blockDim.x) {
        int p = atomicAdd(&cur[dst[i]], 1);
        csrc[p] = src[i];
    }
}

// ---------------------------------------------------------------------------
// Fused weight prep + graph_offsets (one launch)
// ---------------------------------------------------------------------------
struct PrepArgs {
    const float *projW, *convWn, *convWs, *Wih0, *Whh0, *Wih1, *Whh1;
    const int* gid;
    unsigned short *pBth, *pBtl;
    unsigned short *WnTh0, *WnTl0, *WnTh1, *WnTl1;
    unsigned short *WsTh0, *WsTl0, *WsTh1, *WsTl1;
    float *WihT0, *WhhT0, *WihT1, *WhhT1;
    int* goffs;
};

__device__ inline void wsplit(const float* B, int K, int N, int idx,
                              unsigned short* Bth, unsigned short* Btl) {
    int k = idx / N, n = idx - k * N;
    float v = B[idx];
    unsigned short h = bf16_rne(v);
    unsigned short l = bf16_rne(v - bf16_f(h));
    Bth[(size_t)n * K + k] = h;
    Btl[(size_t)n * K + k] = l;
}
__device__ inline void gruT(const float* W, int K, int idx, float* WT) {
    int d = idx / (384 * K);
    int r = idx - d * 384 * K;
    int j = r / K, k = r - j * K;
    WT[(size_t)d * K * 384 + (size_t)k * 384 + j] = W[idx];
}

__global__ void prep_all(PrepArgs a) {
    int i = blockIdx.x * blockDim.x + threadIdx.x;
    if (i < 16384)  { wsplit(a.projW, 128, 128, i, a.pBth, a.pBtl); return; }   i -= 16384;
    if (i < 49152)  { wsplit(a.convWn, 128, 384, i, a.WnTh0, a.WnTl0); return; } i -= 49152;
    if (i < 49152)  { wsplit(a.convWn + 49152, 128, 384, i, a.WnTh1, a.WnTl1); return; } i -= 49152;
    if (i < 49152)  { wsplit(a.convWs, 384, 128, i, a.WsTh0, a.WsTl0); return; } i -= 49152;
    if (i < 49152)  { wsplit(a.convWs + 49152, 384, 128, i, a.WsTh1, a.WsTl1); return; } i -= 49152;
    if (i < 98304)  { gruT(a.Wih0, 128, i, a.WihT0); return; }  i -= 98304;
    if (i < 98304)  { gruT(a.Whh0, 128, i, a.WhhT0); return; }  i -= 98304;
    if (i < 196608) { gruT(a.Wih1, 256, i, a.WihT1); return; }  i -= 196608;
    if (i < 98304)  { gruT(a.Whh1, 128, i, a.WhhT1); return; }  i -= 98304;
    if (i < Nn) {
        int g = a.gid[i];
        if (i == 0) { for (int b = 0; b <= g; b++) a.goffs[b] = 0; }
        else { int pg = a.gid[i - 1]; for (int b = pg + 1; b <= g; b++) a.goffs[b] = i; }
        if (i == Nn - 1) { for (int b = g + 1; b <= Bb; b++) a.goffs[b] = Nn; }
    }
}

// ---------------------------------------------------------------------------
// Split-bf16 MFMA GEMM with fused epilogues. BN=128 always; 256 threads.
// MODE 0: proj, BM=32 (1x4 waves, wave tile 32x32): hcur = acc+bias+projW[wid];
//         fused per-graph readout accumulation (gid sorted, atomic per run).
// MODE 1: Wn+att, BM=64 (2x2 waves, wave tile 32x64): wv bf16 = acc+bias;
//         per-head att dots from fp32 acc -> ad/add.
// MODE 2: Ws+LN, BM=32: x = hcur + (deg>0 ? acc+bias : 0); LayerNorm; ReLU;
//         fused readout accumulation.
// ---------------------------------------------------------------------------
struct GArgs {
    const float* A; const unsigned short* Bth; const unsigned short* Btl;
    const float* bias; int M, N, K;
    const int* wid; const float* projW;                 // MODE 0
    unsigned short* Cb; float* adf; float* addf; const float* att;  // MODE 1
    const int* deg; const float* gamma; const float* beta;          // MODE 2
    float* hcur;
    const int* gid; float* reado;                       // MODE 0/2 readout
};

template <int MODE>
__global__ __launch_bounds__(256) void gemm_fused(GArgs a) {
    constexpr int WM = (MODE == 1) ? 2 : 1;
    constexpr int WN = 4 / WM;
    constexpr int MI = 2;
    constexpr int NI = (MODE == 1) ? 4 : 2;
    constexpr int BM = WM * MI * 16;        // 64 (MODE1) or 32 (MODE0/2)
    __shared__ unsigned short As_hi[BM][40];
    __shared__ unsigned short As_lo[BM][40];
    __shared__ unsigned short Bs_hi[128][40];
    __shared__ unsigned short Bs_lo[128][40];
    const int tid  = threadIdx.x;
    const int row0 = blockIdx.y * BM;
    const int col0 = blockIdx.x * 128;
    const int w    = tid >> 6;
    const int wm   = w / WN;
    const int wn   = w % WN;
    const int L    = tid & 63;
    const int lrow = L & 15;
    const int lq   = L >> 4;
    const int M = a.M, N = a.N, K = a.K;

    f32x4 acc[MI][NI];
#pragma unroll
    for (int i = 0; i < MI; i++)
#pragma unroll
        for (int j = 0; j < NI; j++) acc[i][j] = (f32x4){0.f, 0.f, 0.f, 0.f};

    for (int kb = 0; kb < K; kb += 32) {
        // ---- stage A (fp32 -> hi/lo bf16), BM x 32 ----
#pragma unroll
        for (int it = 0; it < BM / 32; it++) {
            int idx = tid + it * 256;          // < BM*8
            int m  = idx >> 3;
            int kq = (idx & 7) * 4;
            int gr = row0 + m;
            float4 v = make_float4(0.f, 0.f, 0.f, 0.f);
            if (gr < M) v = *(const float4*)(a.A + (size_t)gr * K + kb + kq);
            unsigned short h0 = bf16_rne(v.x), h1 = bf16_rne(v.y),
                           h2 = bf16_rne(v.z), h3 = bf16_rne(v.w);
            short4 hi4 = make_short4((short)h0, (short)h1, (short)h2, (short)h3);
            short4 lo4 = make_short4((short)bf16_rne(v.x - bf16_f(h0)),
                                     (short)bf16_rne(v.y - bf16_f(h1)),
                                     (short)bf16_rne(v.z - bf16_f(h2)),
                                     (short)bf16_rne(v.w - bf16_f(h3)));
            *(short4*)&As_hi[m][kq] = hi4;
            *(short4*)&As_lo[m][kq] = lo4;
        }
        // ---- stage B^T (bf16 hi/lo), 128 n x 32 k ----
        {
            int n  = tid >> 1;
            int kh = (tid & 1) * 16;
            const unsigned short* sh = a.Bth + (size_t)(col0 + n) * K + kb + kh;
            const unsigned short* sl = a.Btl + (size_t)(col0 + n) * K + kb + kh;
            *(float4*)&Bs_hi[n][kh]     = *(const float4*)sh;
            *(float4*)&Bs_hi[n][kh + 8] = *(const float4*)(sh + 8);
            *(float4*)&Bs_lo[n][kh]     = *(const float4*)sl;
            *(float4*)&Bs_lo[n][kh + 8] = *(const float4*)(sl + 8);
        }
        __syncthreads();
        bf16x8 ah[MI], al[MI], bh[NI], bl[NI];
#pragma unroll
        for (int mi = 0; mi < MI; mi++) {
            int r = wm * 32 + mi * 16 + lrow;
            ah[mi] = *(const bf16x8*)&As_hi[r][lq * 8];
            al[mi] = *(const bf16x8*)&As_lo[r][lq * 8];
        }
#pragma unroll
        for (int ni = 0; ni < NI; ni++) {
            int r = wn * NI * 16 + ni * 16 + lrow;
            bh[ni] = *(const bf16x8*)&Bs_hi[r][lq * 8];
            bl[ni] = *(const bf16x8*)&Bs_lo[r][lq * 8];
        }
#pragma unroll
        for (int mi = 0; mi < MI; mi++)
#pragma unroll
            for (int ni = 0; ni < NI; ni++) {
                acc[mi][ni] = __builtin_amdgcn_mfma_f32_16x16x32_bf16(ah[mi], bh[ni], acc[mi][ni], 0, 0, 0);
                acc[mi][ni] = __builtin_amdgcn_mfma_f32_16x16x32_bf16(ah[mi], bl[ni], acc[mi][ni], 0, 0, 0);
                acc[mi][ni] = __builtin_amdgcn_mfma_f32_16x16x32_bf16(al[mi], bh[ni], acc[mi][ni], 0, 0, 0);
            }
        __syncthreads();
    }

    // ---- bias (per col) ----
    float b4[NI];
#pragma unroll
    for (int ni = 0; ni < NI; ni++)
        b4[ni] = a.bias ? a.bias[col0 + wn * NI * 16 + ni * 16 + lrow] : 0.f;
#pragma unroll
    for (int mi = 0; mi < MI; mi++)
#pragma unroll
        for (int ni = 0; ni < NI; ni++)
#pragma unroll
            for (int r = 0; r < 4; r++) acc[mi][ni][r] += b4[ni];

    if constexpr (MODE == 0) {
        // hcur = acc + projW[wid[row]]; ytile for readout
        __shared__ float ytile[32][132];
        __shared__ int sgid[32];
#pragma unroll
        for (int mi = 0; mi < MI; mi++)
#pragma unroll
            for (int r = 0; r < 4; r++) {
                int lr = mi * 16 + lq * 4 + r;      // wm == 0
                int row = row0 + lr;                // always < M (20000 % 32 == 0)
                int wi = a.wid[row];
#pragma unroll
                for (int ni = 0; ni < NI; ni++) {
                    int c = wn * 32 + ni * 16 + lrow;
                    float y = acc[mi][ni][r] + a.projW[(size_t)wi * 128 + c];
                    a.hcur[(size_t)row * 128 + c] = y;
                    ytile[lr][c] = y;
                }
            }
        if (tid < 32) sgid[tid] = a.gid[row0 + tid];
        __syncthreads();
        int j = tid & 127, hh = tid >> 7;
        float sum = 0.f; int curg = -1;
        for (int r = hh * 16; r < hh * 16 + 16; r++) {
            int g = sgid[r];
            if (g != curg) {
                if (curg >= 0) atomicAdd(&a.reado[(size_t)curg * 128 + j], sum);
                sum = 0.f; curg = g;
            }
            sum += ytile[r][j];
        }
        if (curg >= 0) atomicAdd(&a.reado[(size_t)curg * 128 + j], sum);
    }

    if constexpr (MODE == 1) {
        // bf16 wv write
#pragma unroll
        for (int mi = 0; mi < MI; mi++)
#pragma unroll
            for (int ni = 0; ni < NI; ni++) {
                int col = col0 + wn * 64 + ni * 16 + lrow;
#pragma unroll
                for (int r = 0; r < 4; r++) {
                    int row = row0 + wm * 32 + mi * 16 + lq * 4 + r;
                    if (row < M) a.Cb[(size_t)row * N + col] = bf16_rne(acc[mi][ni][r]);
                }
            }
        // att dots for this head (blockIdx.x = head)
        const int h = blockIdx.x;
        const float* attS = a.att + h * 256;
        const float* attD = attS + 128;
        __shared__ float sred[64][2], dred[64][2];
        float as4[NI], ad4[NI];
#pragma unroll
        for (int ni = 0; ni < NI; ni++) {
            int cl = wn * 64 + ni * 16 + lrow;
            as4[ni] = attS[cl]; ad4[ni] = attD[cl];
        }
#pragma unroll
        for (int mi = 0; mi < MI; mi++)
#pragma unroll
            for (int r = 0; r < 4; r++) {
                float ps = 0.f, pd = 0.f;
#pragma unroll
                for (int ni = 0; ni < NI; ni++) {
                    ps += acc[mi][ni][r] * as4[ni];
                    pd += acc[mi][ni][r] * ad4[ni];
                }
#pragma unroll
                for (int o = 1; o < 16; o <<= 1) {
                    ps += __shfl_xor(ps, o, 64);
                    pd += __shfl_xor(pd, o, 64);
                }
                if (lrow == 0) {
                    int lr = wm * 32 + mi * 16 + lq * 4 + r;
                    sred[lr][wn] = ps; dred[lr][wn] = pd;
                }
            }
        __syncthreads();
        if (tid < 64) {
            int row = row0 + tid;
            if (row < M) {
                a.adf[(size_t)row * 4 + h]  = sred[tid][0] + sred[tid][1];
                a.addf[(size_t)row * 4 + h] = dred[tid][0] + dred[tid][1];
            }
        }
    }

    if constexpr (MODE == 2) {
        __shared__ float red1[32][4], red2[32][4];
        __shared__ float ytile[32][132];
        __shared__ int sgid[32];
        float g4[NI], be4[NI];
#pragma unroll
        for (int ni = 0; ni < NI; ni++) {
            int c = wn * 32 + ni * 16 + lrow;
            g4[ni] = a.gamma[c]; be4[ni] = a.beta[c];
        }
        // x = hcur_old + (deg>0 ? acc : 0)
#pragma unroll
        for (int mi = 0; mi < MI; mi++)
#pragma unroll
            for (int r = 0; r < 4; r++) {
                int lr = mi * 16 + lq * 4 + r;
                int row = row0 + lr;
                int dg = a.deg[row];
#pragma unroll
                for (int ni = 0; ni < NI; ni++) {
                    int c = wn * 32 + ni * 16 + lrow;
                    float hold = a.hcur[(size_t)row * 128 + c];
                    acc[mi][ni][r] = hold + (dg > 0 ? acc[mi][ni][r] : 0.f);
                }
            }
        // mean
#pragma unroll
        for (int mi = 0; mi < MI; mi++)
#pragma unroll
            for (int r = 0; r < 4; r++) {
                float ps = acc[mi][0][r] + acc[mi][1][r];
#pragma unroll
                for (int o = 1; o < 16; o <<= 1) ps += __shfl_xor(ps, o, 64);
                if (lrow == 0) red1[mi * 16 + lq * 4 + r][wn] = ps;
            }
        __syncthreads();
        // var
#pragma unroll
        for (int mi = 0; mi < MI; mi++)
#pragma unroll
            for (int r = 0; r < 4; r++) {
                int lr = mi * 16 + lq * 4 + r;
                float mu = (red1[lr][0] + red1[lr][1] + red1[lr][2] + red1[lr][3]) * (1.f / 128.f);
                float qs = 0.f;
#pragma unroll
                for (int ni = 0; ni < NI; ni++) {
                    float dx = acc[mi][ni][r] - mu;
                    qs += dx * dx;
                }
#pragma unroll
                for (int o = 1; o < 16; o <<= 1) qs += __shfl_xor(qs, o, 64);
                if (lrow == 0) red2[lr][wn] = qs;
            }
        __syncthreads();
        // normalize + relu + write + ytile
#pragma unroll
        for (int mi = 0; mi < MI; mi++)
#pragma unroll
            for (int r = 0; r < 4; r++) {
                int lr = mi * 16 + lq * 4 + r;
                int row = row0 + lr;
                float mu = (red1[lr][0] + red1[lr][1] + red1[lr][2] + red1[lr][3]) * (1.f / 128.f);
                float var = (red2[lr][0] + red2[lr][1] + red2[lr][2] + red2[lr][3]) * (1.f / 128.f);
                float rs = rsqrtf(var + EPS);
#pragma unroll
                for (int ni = 0; ni < NI; ni++) {
                    int c = wn * 32 + ni * 16 + lrow;
                    float y = fmaxf((acc[mi][ni][r] - mu) * rs * g4[ni] + be4[ni], 0.f);
                    a.hcur[(size_t)row * 128 + c] = y;
                    ytile[lr][c] = y;
                }
            }
        if (tid < 32) sgid[tid] = a.gid[row0 + tid];
        __syncthreads();
        int j = tid & 127, hh = tid >> 7;
        float sum = 0.f; int curg = -1;
        for (int r = hh * 16; r < hh * 16 + 16; r++) {
            int g = sgid[r];
            if (g != curg) {
                if (curg >= 0) atomicAdd(&a.reado[(size_t)curg * 128 + j], sum);
                sum = 0.f; curg = g;
            }
            sum += ytile[r][j];
        }
        if (curg >= 0) atomicAdd(&a.reado[(size_t)curg * 128 + j], sum);
    }
}

// ---------------------------------------------------------------------------
// GAT softmax-attention aggregation, one wave per dst node, bf16 wv gather.
// ---------------------------------------------------------------------------
__global__ __launch_bounds__(256) void gat_aggregate(const unsigned short* __restrict__ wv,
                                                     const float4* __restrict__ ad,
                                                     const float4* __restrict__ add,
                                                     const int* __restrict__ offs,
                                                     const int* __restrict__ csrc,
                                                     float* __restrict__ agg) {
    const int n = (blockIdx.x * 256 + threadIdx.x) >> 6;
    const int L = threadIdx.x & 63;
    if (n >= Nn) return;
    const int start = offs[n];
    const int deg = offs[n + 1] - start;
    float2* o2 = (float2*)(agg + (size_t)n * 384);
    if (deg == 0) {
        float2 z = make_float2(0.f, 0.f);
        o2[L] = z; o2[64 + L] = z; o2[128 + L] = z;
        return;
    }
    const float4 adn = add[n];
    float m0 = -1e30f, m1 = -1e30f, m2 = -1e30f;
    float s0 = 0.f, s1 = 0.f, s2 = 0.f;
    for (int i = L; i < deg; i += 64) {
        int sn = csrc[start + i];
        float4 a4 = ad[sn];
        float a0 = lrelu(a4.x + adn.x);
        float a1 = lrelu(a4.y + adn.y);
        float a2 = lrelu(a4.z + adn.z);
        float nm;
        nm = fmaxf(m0, a0); s0 = s0 * __expf(m0 - nm) + __expf(a0 - nm); m0 = nm;
        nm = fmaxf(m1, a1); s1 = s1 * __expf(m1 - nm) + __expf(a1 - nm); m1 = nm;
        nm = fmaxf(m2, a2); s2 = s2 * __expf(m2 - nm) + __expf(a2 - nm); m2 = nm;
    }
#pragma unroll
    for (int o = 32; o > 0; o >>= 1) {
        float om, os, nm;
        om = __shfl_xor(m0, o, 64); os = __shfl_xor(s0, o, 64);
        nm = fmaxf(m0, om); s0 = s0 * __expf(m0 - nm) + os * __expf(om - nm); m0 = nm;
        om = __shfl_xor(m1, o, 64); os = __shfl_xor(s1, o, 64);
        nm = fmaxf(m1, om); s1 = s1 * __expf(m1 - nm) + os * __expf(om - nm); m1 = nm;
        om = __shfl_xor(m2, o, 64); os = __shfl_xor(s2, o, 64);
        nm = fmaxf(m2, om); s2 = s2 * __expf(m2 - nm) + os * __expf(om - nm); m2 = nm;
    }
    const float i0 = 1.f / s0, i1 = 1.f / s1, i2 = 1.f / s2;
    float2 acc0 = make_float2(0.f, 0.f), acc1 = acc0, acc2 = acc0;
    for (int base = 0; base < deg; base += 64) {
        int cnt = deg - base; if (cnt > 64) cnt = 64;
        int sn = 0; float c0 = 0.f, c1 = 0.f, c2 = 0.f;
        if (L < cnt) {
            sn = csrc[start + base + L];
            float4 a4 = ad[sn];
            c0 = __expf(lrelu(a4.x + adn.x) - m0) * i0;
            c1 = __expf(lrelu(a4.y + adn.y) - m1) * i1;
            c2 = __expf(lrelu(a4.z + adn.z) - m2) * i2;
        }
        for (int j = 0; j < cnt; j++) {
            int    s_n = __shfl(sn, j, 64);
            float  w0  = __shfl(c0, j, 64);
            float  w1  = __shfl(c1, j, 64);
            float  w2  = __shfl(c2, j, 64);
            const unsigned* r2 = (const unsigned*)(wv + (size_t)s_n * 384);
            unsigned u0 = r2[L], u1 = r2[64 + L], u2 = r2[128 + L];
            acc0.x += w0 * bf_lo(u0); acc0.y += w0 * bf_hi(u0);
            acc1.x += w1 * bf_lo(u1); acc1.y += w1 * bf_hi(u1);
            acc2.x += w2 * bf_lo(u2); acc2.y += w2 * bf_hi(u2);
        }
    }
    o2[L] = acc0; o2[64 + L] = acc1; o2[128 + L] = acc2;
}

// ---------------------------------------------------------------------------
// Full GRU stack: one block per batch element, 768 threads (2 dirs x 384).
// reado holds per-graph SUMS; divide by node count here.
// ---------------------------------------------------------------------------
__global__ __launch_bounds__(768) void gru_all(const float* __restrict__ reado,
                                               const int* __restrict__ goffs,
                                               const float* __restrict__ WihT0,
                                               const float* __restrict__ WhhT0,
                                               const float* __restrict__ bih0,
                                               const float* __restrict__ bhh0,
                                               const float* __restrict__ WihT1,
                                               const float* __restrict__ WhhT1,
                                               const float* __restrict__ bih1,
                                               const float* __restrict__ bhh1,
                                               float* __restrict__ out) {
    const int b = blockIdx.x;
    const int tid = threadIdx.x;
    const int dir = tid / 384;
    const int j = tid - dir * 384;
    __shared__ float xs[3][128];
    __shared__ float y0s[3][256];
    __shared__ float hs[2][128];
    __shared__ float gil[2][384], ghl[2][384];
    __shared__ float fin01[2][128];
    if (tid < 128) {
        int cnt = goffs[b + 1] - goffs[b];
        float invc = 1.f / fmaxf((float)cnt, 1.f);
#pragma unroll
        for (int t = 0; t < 3; t++)
            xs[t][tid] = reado[(size_t)t * Bb * Hh + (size_t)b * Hh + tid] * invc;
    }
    if (j < 128) hs[dir][j] = 0.f;
    __syncthreads();
    // ---- layer 0 ----
    {
        const float* Wi = WihT0 + (size_t)dir * 128 * 384;
        const float* Wh = WhhT0 + (size_t)dir * 128 * 384;
        float gi[3];
        gi[0] = gi[1] = gi[2] = bih0[dir * 384 + j];
        for (int k = 0; k < 128; k++) {
            float w = Wi[(size_t)k * 384 + j];
            gi[0] += w * xs[0][k]; gi[1] += w * xs[1][k]; gi[2] += w * xs[2][k];
        }
        const float bhj = bhh0[dir * 384 + j];
        for (int step = 0; step < 3; step++) {
            int t = dir ? 2 - step : step;
            float g = bhj;
            for (int k = 0; k < 128; k++) g += Wh[(size_t)k * 384 + j] * hs[dir][k];
            ghl[dir][j] = g;
            gil[dir][j] = gi[t];
            __syncthreads();
            if (j < 128) {
                float r = sigmoidf(gil[dir][j] + ghl[dir][j]);
                float z = sigmoidf(gil[dir][j + 128] + ghl[dir][j + 128]);
                float nn2 = tanhf(gil[dir][j + 256] + r * ghl[dir][j + 256]);
                float hnew = (1.f - z) * nn2 + z * hs[dir][j];
                hs[dir][j] = hnew;
                y0s[t][dir * 128 + j] = hnew;
                if (step == 2) fin01[dir][j] = hnew;
            }
            __syncthreads();
        }
    }
    // ---- layer 1 ----
    if (j < 128) hs[dir][j] = 0.f;
    {
        const float* Wi = WihT1 + (size_t)dir * 256 * 384;
        const float* Wh = WhhT1 + (size_t)dir * 128 * 384;
        float gi[3];
        gi[0] = gi[1] = gi[2] = bih1[dir * 384 + j];
        for (int k = 0; k < 256; k++) {
            float w = Wi[(size_t)k * 384 + j];
            gi[0] += w * y0s[0][k]; gi[1] += w * y0s[1][k]; gi[2] += w * y0s[2][k];
        }
        const float bhj = bhh1[dir * 384 + j];
        __syncthreads();
        for (int step = 0; step < 3; step++) {
            int t = dir ? 2 - step : step;
            float g = bhj;
            for (int k = 0; k < 128; k++) g += Wh[(size_t)k * 384 + j] * hs[dir][k];
            ghl[dir][j] = g;
            gil[dir][j] = gi[t];
            __syncthreads();
            if (j < 128) {
                float r = sigmoidf(gil[dir][j] + ghl[dir][j]);
                float z = sigmoidf(gil[dir][j + 128] + ghl[dir][j + 128]);
                float nn2 = tanhf(gil[dir][j + 256] + r * ghl[dir][j + 256]);
                float hnew = (1.f - z) * nn2 + z * hs[dir][j];
                hs[dir][j] = hnew;
                if (step == 2) xs[dir][j] = hnew;   // reuse xs as fin23
            }
            __syncthreads();
        }
    }
    if (tid < 128)
        out[(size_t)b * Hh + tid] = 0.25f * (fin01[0][tid] + fin01[1][tid] +
                                             xs[0][tid] + xs[1][tid]);
}

// ---------------------------------------------------------------------------
extern "C" void kernel_launch(void* const* d_in, const int* in_sizes, int n_in,
                              void* d_out, int out_size, void* d_ws, size_t ws_size,
                              hipStream_t stream) {
    const float* h      = (const float*)d_in[0];
    const int*   wid    = (const int*)d_in[1];
    const int*   src    = (const int*)d_in[2];
    const int*   dst    = (const int*)d_in[3];
    const int*   gid    = (const int*)d_in[4];
    const float* projW  = (const float*)d_in[5];
    const float* projB  = (const float*)d_in[6];
    const float* convWn = (const float*)d_in[7];
    const float* convBn = (const float*)d_in[8];
    const float* convAtt= (const float*)d_in[9];
    const float* convWs = (const float*)d_in[10];
    const float* convB  = (const float*)d_in[11];
    const float* convG  = (const float*)d_in[12];
    const float* convBe = (const float*)d_in[13];
    const float* Wih0   = (const float*)d_in[14];
    const float* Whh0   = (const float*)d_in[15];
    const float* bih0   = (const float*)d_in[16];
    const float* bhh0   = (const float*)d_in[17];
    const float* Wih1   = (const float*)d_in[18];
    const float* Whh1   = (const float*)d_in[19];
    const float* bih1   = (const float*)d_in[20];
    const float* bhh1   = (const float*)d_in[21];
    float* out = (float*)d_out;

    char* p = (char*)d_ws;
    auto alloc_f = [&](size_t n) { float* r = (float*)p; p += n * sizeof(float); return r; };
    auto alloc_i = [&](size_t n) { int* r = (int*)p; p += n * sizeof(int); return r; };
    auto alloc_s = [&](size_t n) { unsigned short* r = (unsigned short*)p; p += n * sizeof(unsigned short); return r; };
    float* hcur  = alloc_f((size_t)Nn * Hh);
    float* agg   = alloc_f((size_t)Nn * 384);
    float* adbuf = alloc_f((size_t)Nn * 4);
    float* addbuf= alloc_f((size_t)Nn * 4);
    // contiguous zero region: reado (graph sums) | deg
    float* reado = alloc_f((size_t)3 * Bb * Hh);
    int* deg  = alloc_i(Nn);
    const size_t zero_bytes = (size_t)3 * Bb * Hh * sizeof(float) + Nn * sizeof(int);
    float* WihT0 = alloc_f((size_t)2 * 128 * 384);
    float* WhhT0 = alloc_f((size_t)2 * 128 * 384);
    float* WihT1 = alloc_f((size_t)2 * 256 * 384);
    float* WhhT1 = alloc_f((size_t)2 * 128 * 384);
    int* offs = alloc_i(Nn + 1);
    int* cur  = alloc_i(Nn);
    int* csrc = alloc_i(Ee);
    int* goffs = alloc_i(Bb + 1);
    unsigned short* wv = alloc_s((size_t)Nn * 384);
    unsigned short* pBth  = alloc_s(128 * 128);
    unsigned short* pBtl  = alloc_s(128 * 128);
    unsigned short* WnTh[2] = { alloc_s(384 * 128), alloc_s(384 * 128) };
    unsigned short* WnTl[2] = { alloc_s(384 * 128), alloc_s(384 * 128) };
    unsigned short* WsTh[2] = { alloc_s(128 * 384), alloc_s(128 * 384) };
    unsigned short* WsTl[2] = { alloc_s(128 * 384), alloc_s(128 * 384) };

    hipMemsetAsync(reado, 0, zero_bytes, stream);

    hist_dst<<<1250, 256, 0, stream>>>(dst, deg);
    scan_offsets<<<1, 1024, 0, stream>>>(deg, offs, cur);
    fill_csr<<<1250, 256, 0, stream>>>(dst, src, cur, csrc);

    PrepArgs pa;
    pa.projW = projW + (size_t)Vv * Hh; pa.convWn = convWn; pa.convWs = convWs;
    pa.Wih0 = Wih0; pa.Whh0 = Whh0; pa.Wih1 = Wih1; pa.Whh1 = Whh1;
    pa.gid = gid;
    pa.pBth = pBth; pa.pBtl = pBtl;
    pa.WnTh0 = WnTh[0]; pa.WnTl0 = WnTl[0]; pa.WnTh1 = WnTh[1]; pa.WnTl1 = WnTl[1];
    pa.WsTh0 = WsTh[0]; pa.WsTl0 = WsTl[0]; pa.WsTh1 = WsTh[1]; pa.WsTl1 = WsTl[1];
    pa.WihT0 = WihT0; pa.WhhT0 = WhhT0; pa.WihT1 = WihT1; pa.WhhT1 = WhhT1;
    pa.goffs = goffs;
    prep_all<<<(724512 + 255) / 256, 256, 0, stream>>>(pa);

    // projection (BM=32): grid (1, 625)
    {
        GArgs g = {};
        g.A = h; g.Bth = pBth; g.Btl = pBtl; g.bias = projB;
        g.M = Nn; g.N = 128; g.K = 128;
        g.wid = wid; g.projW = projW; g.hcur = hcur;
        g.gid = gid; g.reado = reado;
        gemm_fused<0><<<dim3(1, Nn / 32), 256, 0, stream>>>(g);
    }

    const int nwaveblocks = (Nn * 64 + 255) / 256;   // 5000
    for (int l = 0; l < 2; l++) {
        {   // Wn + att dots (BM=64): grid (3, 313)
            GArgs g = {};
            g.A = hcur; g.Bth = WnTh[l]; g.Btl = WnTl[l]; g.bias = convBn + l * 384;
            g.M = Nn; g.N = 384; g.K = 128;
            g.Cb = wv; g.adf = adbuf; g.addf = addbuf;
            g.att = convAtt + (size_t)l * 3 * 256;
            gemm_fused<1><<<dim3(3, (Nn + 63) / 64), 256, 0, stream>>>(g);
        }
        gat_aggregate<<<nwaveblocks, 256, 0, stream>>>(wv, (const float4*)adbuf, (const float4*)addbuf,
                                                       offs, csrc, agg);
        {   // Ws + LN + readout (BM=32): grid (1, 625)
            GArgs g = {};
            g.A = agg; g.Bth = WsTh[l]; g.Btl = WsTl[l]; g.bias = convB + l * Hh;
            g.M = Nn; g.N = 128; g.K = 384;
            g.deg = deg; g.gamma = convG + l * Hh; g.beta = convBe + l * Hh;
            g.hcur = hcur;
            g.gid = gid; g.reado = reado + (size_t)(l + 1) * Bb * Hh;
            gemm_fused<2><<<dim3(1, Nn / 32), 256, 0, stream>>>(g);
        }
    }

    gru_all<<<Bb, 768, 0, stream>>>(reado, goffs, WihT0, WhhT0, bih0, bhh0,
                                    WihT1, WhhT1, bih1, bhh1, out);
}

// Round 9
// 377.025 us; speedup vs baseline: 1.5738x; 1.1021x over previous
//
#include <hip/hip_runtime.h>
#include <cstddef>
#include <cstdint>

// Problem constants (from reference)
static constexpr int Nn    = 20000;
static constexpr int Ee    = 320000;
static constexpr int Vv    = 100;
static constexpr int Hh    = 128;
static constexpr int HEADS = 3;
static constexpr int Bb    = 200;
static constexpr float NEG = 0.2f;
static constexpr float EPS = 1e-5f;

typedef short bf16x8 __attribute__((ext_vector_type(8)));
typedef float f32x4  __attribute__((ext_vector_type(4)));

__device__ inline unsigned short bf16_rne(float x) {
    unsigned u = __builtin_bit_cast(unsigned, x);
    u += 0x7FFFu + ((u >> 16) & 1u);
    return (unsigned short)(u >> 16);
}
__device__ inline float bf16_f(unsigned short h) {
    unsigned u = ((unsigned)h) << 16;
    return __builtin_bit_cast(float, u);
}
__device__ inline float bf_lo(unsigned u) { return __builtin_bit_cast(float, u << 16); }
__device__ inline float bf_hi(unsigned u) { return __builtin_bit_cast(float, u & 0xFFFF0000u); }
__device__ inline float lrelu(float a) { return a >= 0.f ? a : NEG * a; }
__device__ inline float sigmoidf(float x) { return 1.f / (1.f + __expf(-x)); }

// ---------------------------------------------------------------------------
// CSR scan + fill (hist merged into prep_all)
// ---------------------------------------------------------------------------
__global__ __launch_bounds__(1024) void scan_offsets(const int* __restrict__ deg,
                                                     int* __restrict__ offs,
                                                     int* __restrict__ cur) {
    __shared__ int sums[1024];
    const int tid = threadIdx.x;
    const int per = (Nn + 1023) >> 10;
    int begin = tid * per;
    int end = begin + per; if (end > Nn) end = Nn;
    if (begin > Nn) begin = Nn;
    int s = 0;
    for (int i = begin; i < end; i++) s += deg[i];
    sums[tid] = s;
    __syncthreads();
    for (int off = 1; off < 1024; off <<= 1) {
        int v = (tid >= off) ? sums[tid - off] : 0;
        __syncthreads();
        sums[tid] += v;
        __syncthreads();
    }
    int run = sums[tid] - s;
    for (int i = begin; i < end; i++) {
        offs[i] = run; cur[i] = run;
        run += deg[i];
    }
    if (end == Nn) offs[Nn] = run;
}

__global__ void fill_csr(const int* __restrict__ dst, const int* __restrict__ src,
                         int* __restrict__ cur, int* __restrict__ csrc) {
    for (int i = blockIdx.x * blockDim.x + threadIdx.x; i < Ee; i += gridDim.x * blockDim.x) {
        int p = atomicAdd(&cur[dst[i]], 1);
        csrc[p] = src[i];
    }
}

// ---------------------------------------------------------------------------
// Fused prep: projW split; Wfused = blockdiag(Wn)@Ws split-transposed;
// va/vd = Wn_h @ att halves; vc = bn_h . att halves; biasF = convB + bn@Ws;
// GRU weight transposes; graph offsets; dst histogram.
// ---------------------------------------------------------------------------
struct PrepArgs {
    const float *projW, *convWn, *convWs, *convAtt, *convBn, *convB;
    const float *Wih0, *Whh0, *Wih1, *Whh1;
    const int *gid, *dst;
    unsigned short *pBth, *pBtl;
    unsigned short *WfTh0, *WfTl0, *WfTh1, *WfTl1;
    float *vavd, *vc, *biasF;
    float *WihT0, *WhhT0, *WihT1, *WhhT1;
    int *goffs, *deg;
};

__device__ inline void wsplit(const float* B, int K, int N, int idx,
                              unsigned short* Bth, unsigned short* Btl) {
    int k = idx / N, n = idx - k * N;
    float v = B[idx];
    unsigned short h = bf16_rne(v);
    unsigned short l = bf16_rne(v - bf16_f(h));
    Bth[(size_t)n * K + k] = h;
    Btl[(size_t)n * K + k] = l;
}
__device__ inline void gruT(const float* W, int K, int idx, float* WT) {
    int d = idx / (384 * K);
    int r = idx - d * 384 * K;
    int j = r / K, k = r - j * K;
    WT[(size_t)d * K * 384 + (size_t)k * 384 + j] = W[idx];
}

__global__ void prep_all(PrepArgs a) {
    int i = blockIdx.x * blockDim.x + threadIdx.x;
    if (i < 16384) { wsplit(a.projW, 128, 128, i, a.pBth, a.pBtl); return; } i -= 16384;
    // Wfused per layer: Wf[k=h*128+i_][c] = sum_j Wn[i_][h*128+j]*Ws[h*128+j][c]
#pragma unroll
    for (int l = 0; l < 2; l++) {
        if (i < 49152) {
            int k = i >> 7, c = i & 127;
            int h = k >> 7, i_ = k & 127;
            const float* wn = a.convWn + (size_t)l * 49152 + (size_t)i_ * 384 + h * 128;
            const float* ws = a.convWs + (size_t)l * 49152 + (size_t)(h * 128) * 128 + c;
            float v = 0.f;
            for (int j = 0; j < 128; j++) v += wn[j] * ws[(size_t)j * 128];
            unsigned short hi = bf16_rne(v);
            unsigned short lo = bf16_rne(v - bf16_f(hi));
            unsigned short* th = l ? a.WfTh1 : a.WfTh0;
            unsigned short* tl = l ? a.WfTl1 : a.WfTl0;
            th[(size_t)c * 384 + k] = hi;
            tl[(size_t)c * 384 + k] = lo;
            return;
        }
        i -= 49152;
    }
    // va/vd: vavd[((l*2+sd)*3+h)*128 + i_]
    if (i < 1536) {
        int l = i / 768, r = i % 768;
        int sd = r / 384, rr = r % 384, h = rr >> 7, i_ = rr & 127;
        const float* wn = a.convWn + (size_t)l * 49152 + (size_t)i_ * 384 + h * 128;
        const float* at = a.convAtt + l * 768 + h * 256 + sd * 128;
        float v = 0.f;
        for (int j = 0; j < 128; j++) v += wn[j] * at[j];
        a.vavd[i] = v;
        return;
    } i -= 1536;
    // vc: vc[l*6 + sd*3 + h]
    if (i < 12) {
        int l = i / 6, r = i % 6, sd = r / 3, h = r % 3;
        const float* bn = a.convBn + l * 384 + h * 128;
        const float* at = a.convAtt + l * 768 + h * 256 + sd * 128;
        float v = 0.f;
        for (int j = 0; j < 128; j++) v += bn[j] * at[j];
        a.vc[i] = v;
        return;
    } i -= 12;
    // biasF[l*128+c] = convB + sum_k bn[k]*Ws[k][c]
    if (i < 256) {
        int l = i >> 7, c = i & 127;
        const float* bn = a.convBn + l * 384;
        const float* ws = a.convWs + (size_t)l * 49152 + c;
        float v = a.convB[l * 128 + c];
        for (int k = 0; k < 384; k++) v += bn[k] * ws[(size_t)k * 128];
        a.biasF[i] = v;
        return;
    } i -= 256;
    if (i < 98304)  { gruT(a.Wih0, 128, i, a.WihT0); return; }  i -= 98304;
    if (i < 98304)  { gruT(a.Whh0, 128, i, a.WhhT0); return; }  i -= 98304;
    if (i < 196608) { gruT(a.Wih1, 256, i, a.WihT1); return; }  i -= 196608;
    if (i < 98304)  { gruT(a.Whh1, 128, i, a.WhhT1); return; }  i -= 98304;
    if (i < Nn) {
        int g = a.gid[i];
        if (i == 0) { for (int b = 0; b <= g; b++) a.goffs[b] = 0; }
        else { int pg = a.gid[i - 1]; for (int b = pg + 1; b <= g; b++) a.goffs[b] = i; }
        if (i == Nn - 1) { for (int b = g + 1; b <= Bb; b++) a.goffs[b] = Nn; }
        return;
    } i -= Nn;
    if (i < Ee) atomicAdd(&a.deg[a.dst[i]], 1);
}

// ---------------------------------------------------------------------------
// Split-bf16 MFMA GEMM, BM=32, BN=128, BK=32; 256 threads = 4 waves (1x4),
// wave tile 32x32 (2x2 MFMA 16x16x32). Fused epilogues:
// MODE 0: proj: hcur = acc+bias+projW[wid]; MODE 2: residual+LN+ReLU.
// Both: fused per-graph readout; optional next-layer att dots + bf16 plane.
// ---------------------------------------------------------------------------
struct GArgs {
    const float* A; const unsigned short* Bth; const unsigned short* Btl;
    const float* bias; int M, K;
    const int* wid; const float* projW;                 // MODE 0
    const int* deg; const float* gamma; const float* beta;  // MODE 2
    float* hcur;
    const int* gid; float* reado;
    const float* vavd; const float* vc;                 // null -> skip dots/hb
    float* adf; float* addf;
    unsigned short* hb;
};

template <int MODE>
__global__ __launch_bounds__(256) void gemm_fused(GArgs a) {
    __shared__ unsigned short As_hi[32][40];
    __shared__ unsigned short As_lo[32][40];
    __shared__ unsigned short Bs_hi[128][40];
    __shared__ unsigned short Bs_lo[128][40];
    __shared__ float ytile[32][132];
    __shared__ int sgid[32];
    const int tid  = threadIdx.x;
    const int row0 = blockIdx.y * 32;
    const int wn   = tid >> 6;          // wave 0..3 along N
    const int L    = tid & 63;
    const int lrow = L & 15;
    const int lq   = L >> 4;
    const int K = a.K;

    f32x4 acc[2][2];
#pragma unroll
    for (int i = 0; i < 2; i++)
#pragma unroll
        for (int j = 0; j < 2; j++) acc[i][j] = (f32x4){0.f, 0.f, 0.f, 0.f};

    for (int kb = 0; kb < K; kb += 32) {
        {   // stage A 32x32
            int m  = tid >> 3;
            int kq = (tid & 7) * 4;
            float4 v = *(const float4*)(a.A + (size_t)(row0 + m) * K + kb + kq);
            unsigned short h0 = bf16_rne(v.x), h1 = bf16_rne(v.y),
                           h2 = bf16_rne(v.z), h3 = bf16_rne(v.w);
            *(short4*)&As_hi[m][kq] = make_short4((short)h0, (short)h1, (short)h2, (short)h3);
            *(short4*)&As_lo[m][kq] = make_short4((short)bf16_rne(v.x - bf16_f(h0)),
                                                  (short)bf16_rne(v.y - bf16_f(h1)),
                                                  (short)bf16_rne(v.z - bf16_f(h2)),
                                                  (short)bf16_rne(v.w - bf16_f(h3)));
        }
        {   // stage B^T 128x32
            int n  = tid >> 1;
            int kh = (tid & 1) * 16;
            const unsigned short* sh = a.Bth + (size_t)n * K + kb + kh;
            const unsigned short* sl = a.Btl + (size_t)n * K + kb + kh;
            *(float4*)&Bs_hi[n][kh]     = *(const float4*)sh;
            *(float4*)&Bs_hi[n][kh + 8] = *(const float4*)(sh + 8);
            *(float4*)&Bs_lo[n][kh]     = *(const float4*)sl;
            *(float4*)&Bs_lo[n][kh + 8] = *(const float4*)(sl + 8);
        }
        __syncthreads();
        bf16x8 ah[2], al[2], bh[2], bl[2];
#pragma unroll
        for (int mi = 0; mi < 2; mi++) {
            int r = mi * 16 + lrow;
            ah[mi] = *(const bf16x8*)&As_hi[r][lq * 8];
            al[mi] = *(const bf16x8*)&As_lo[r][lq * 8];
        }
#pragma unroll
        for (int ni = 0; ni < 2; ni++) {
            int r = wn * 32 + ni * 16 + lrow;
            bh[ni] = *(const bf16x8*)&Bs_hi[r][lq * 8];
            bl[ni] = *(const bf16x8*)&Bs_lo[r][lq * 8];
        }
#pragma unroll
        for (int mi = 0; mi < 2; mi++)
#pragma unroll
            for (int ni = 0; ni < 2; ni++) {
                acc[mi][ni] = __builtin_amdgcn_mfma_f32_16x16x32_bf16(ah[mi], bh[ni], acc[mi][ni], 0, 0, 0);
                acc[mi][ni] = __builtin_amdgcn_mfma_f32_16x16x32_bf16(ah[mi], bl[ni], acc[mi][ni], 0, 0, 0);
                acc[mi][ni] = __builtin_amdgcn_mfma_f32_16x16x32_bf16(al[mi], bh[ni], acc[mi][ni], 0, 0, 0);
            }
        __syncthreads();
    }

    // bias
#pragma unroll
    for (int ni = 0; ni < 2; ni++) {
        float bb = a.bias[wn * 32 + ni * 16 + lrow];
#pragma unroll
        for (int mi = 0; mi < 2; mi++)
#pragma unroll
            for (int r = 0; r < 4; r++) acc[mi][ni][r] += bb;
    }

    if constexpr (MODE == 0) {
#pragma unroll
        for (int mi = 0; mi < 2; mi++)
#pragma unroll
            for (int r = 0; r < 4; r++) {
                int lr = mi * 16 + lq * 4 + r;
                int row = row0 + lr;
                int wi = a.wid[row];
#pragma unroll
                for (int ni = 0; ni < 2; ni++) {
                    int c = wn * 32 + ni * 16 + lrow;
                    float y = acc[mi][ni][r] + a.projW[(size_t)wi * 128 + c];
                    a.hcur[(size_t)row * 128 + c] = y;
                    ytile[lr][c] = y;
                }
            }
    }

    if constexpr (MODE == 2) {
        __shared__ float red1[32][4], red2[32][4];
        float g4[2], be4[2];
#pragma unroll
        for (int ni = 0; ni < 2; ni++) {
            int c = wn * 32 + ni * 16 + lrow;
            g4[ni] = a.gamma[c]; be4[ni] = a.beta[c];
        }
#pragma unroll
        for (int mi = 0; mi < 2; mi++)
#pragma unroll
            for (int r = 0; r < 4; r++) {
                int lr = mi * 16 + lq * 4 + r;
                int row = row0 + lr;
                int dg = a.deg[row];
#pragma unroll
                for (int ni = 0; ni < 2; ni++) {
                    int c = wn * 32 + ni * 16 + lrow;
                    float hold = a.hcur[(size_t)row * 128 + c];
                    acc[mi][ni][r] = hold + (dg > 0 ? acc[mi][ni][r] : 0.f);
                }
            }
#pragma unroll
        for (int mi = 0; mi < 2; mi++)
#pragma unroll
            for (int r = 0; r < 4; r++) {
                float ps = acc[mi][0][r] + acc[mi][1][r];
#pragma unroll
                for (int o = 1; o < 16; o <<= 1) ps += __shfl_xor(ps, o, 64);
                if (lrow == 0) red1[mi * 16 + lq * 4 + r][wn] = ps;
            }
        __syncthreads();
#pragma unroll
        for (int mi = 0; mi < 2; mi++)
#pragma unroll
            for (int r = 0; r < 4; r++) {
                int lr = mi * 16 + lq * 4 + r;
                float mu = (red1[lr][0] + red1[lr][1] + red1[lr][2] + red1[lr][3]) * (1.f / 128.f);
                float qs = 0.f;
#pragma unroll
                for (int ni = 0; ni < 2; ni++) {
                    float dx = acc[mi][ni][r] - mu;
                    qs += dx * dx;
                }
#pragma unroll
                for (int o = 1; o < 16; o <<= 1) qs += __shfl_xor(qs, o, 64);
                if (lrow == 0) red2[lr][wn] = qs;
            }
        __syncthreads();
#pragma unroll
        for (int mi = 0; mi < 2; mi++)
#pragma unroll
            for (int r = 0; r < 4; r++) {
                int lr = mi * 16 + lq * 4 + r;
                int row = row0 + lr;
                float mu = (red1[lr][0] + red1[lr][1] + red1[lr][2] + red1[lr][3]) * (1.f / 128.f);
                float var = (red2[lr][0] + red2[lr][1] + red2[lr][2] + red2[lr][3]) * (1.f / 128.f);
                float rs = rsqrtf(var + EPS);
#pragma unroll
                for (int ni = 0; ni < 2; ni++) {
                    int c = wn * 32 + ni * 16 + lrow;
                    float y = fmaxf((acc[mi][ni][r] - mu) * rs * g4[ni] + be4[ni], 0.f);
                    a.hcur[(size_t)row * 128 + c] = y;
                    ytile[lr][c] = y;
                }
            }
    }

    if (tid < 32) sgid[tid] = a.gid[row0 + tid];
    __syncthreads();

    // fused per-graph readout (gid sorted -> runs, atomic per run)
    {
        int j = tid & 127, hh = tid >> 7;
        float sum = 0.f; int curg = -1;
        for (int r = hh * 16; r < hh * 16 + 16; r++) {
            int g = sgid[r];
            if (g != curg) {
                if (curg >= 0) atomicAdd(&a.reado[(size_t)curg * 128 + j], sum);
                sum = 0.f; curg = g;
            }
            sum += ytile[r][j];
        }
        if (curg >= 0) atomicAdd(&a.reado[(size_t)curg * 128 + j], sum);
    }

    // next-layer attention dots + bf16 hcur plane
    if (a.vavd) {
        int row = tid & 31, which = tid >> 5;   // which in [0,8)
        if (which < 6) {
            const float* v = a.vavd + which * 128;
            float s = 0.f;
            for (int c = 0; c < 128; c++) s += ytile[row][c] * v[c];
            s += a.vc[which];
            int node = row0 + row;
            int sd = which / 3, h = which - sd * 3;
            float* dstp = sd ? a.addf : a.adf;
            dstp[(size_t)node * 4 + h] = s;
        }
        {
            int row = tid >> 3, c0 = (tid & 7) * 16;
            unsigned* dst = (unsigned*)(a.hb + (size_t)(row0 + row) * 128 + c0);
#pragma unroll
            for (int q = 0; q < 8; q++) {
                unsigned lo = bf16_rne(ytile[row][c0 + 2 * q]);
                unsigned hi = bf16_rne(ytile[row][c0 + 2 * q + 1]);
                dst[q] = lo | (hi << 16);
            }
        }
    }
}

// ---------------------------------------------------------------------------
// GAT gather: one wave per dst node. Scores from per-node dots (no max pass —
// logits are O(0.3) here, exp is safe; ratio identical to reference).
// Gathers bf16 hcur rows (256B), accumulates T[n][h][:] in fp32.
// ---------------------------------------------------------------------------
__global__ __launch_bounds__(256) void gat_gather(const unsigned short* __restrict__ hb,
                                                  const float4* __restrict__ ad,
                                                  const float4* __restrict__ add,
                                                  const int* __restrict__ offs,
                                                  const int* __restrict__ csrc,
                                                  float* __restrict__ T) {
    __shared__ float4 slot[4][64];
    const int n = (blockIdx.x * 256 + threadIdx.x) >> 6;
    const int wv_ = threadIdx.x >> 6;
    const int L = threadIdx.x & 63;
    if (n >= Nn) return;
    const int start = offs[n];
    const int deg = offs[n + 1] - start;
    float2* o2 = (float2*)(T + (size_t)n * 384);
    if (deg == 0) {
        float2 z = make_float2(0.f, 0.f);
        o2[L] = z; o2[64 + L] = z; o2[128 + L] = z;
        return;
    }
    const float4 adn = add[n];
    float2 t0 = make_float2(0.f, 0.f), t1 = t0, t2 = t0;

    if (deg <= 64) {
        int sn = 0; float e0 = 0.f, e1 = 0.f, e2 = 0.f;
        if (L < deg) {
            sn = csrc[start + L];
            float4 a4 = ad[sn];
            e0 = __expf(lrelu(a4.x + adn.x));
            e1 = __expf(lrelu(a4.y + adn.y));
            e2 = __expf(lrelu(a4.z + adn.z));
        }
        float s0 = e0, s1 = e1, s2 = e2;
#pragma unroll
        for (int o = 32; o > 0; o >>= 1) {
            s0 += __shfl_xor(s0, o, 64);
            s1 += __shfl_xor(s1, o, 64);
            s2 += __shfl_xor(s2, o, 64);
        }
        slot[wv_][L] = make_float4(__builtin_bit_cast(float, sn),
                                   e0 / s0, e1 / s1, e2 / s2);
        __builtin_amdgcn_wave_barrier();
#pragma unroll 2
        for (int j = 0; j < deg; j++) {
            float4 sc = slot[wv_][j];
            int s_n = __builtin_bit_cast(int, sc.x);
            unsigned u = ((const unsigned*)(hb + (size_t)s_n * 128))[L];
            float x0 = bf_lo(u), x1 = bf_hi(u);
            t0.x += sc.y * x0; t0.y += sc.y * x1;
            t1.x += sc.z * x0; t1.y += sc.z * x1;
            t2.x += sc.w * x0; t2.y += sc.w * x1;
        }
    } else {
        float s0 = 0.f, s1 = 0.f, s2 = 0.f;
        for (int i = L; i < deg; i += 64) {
            int sn = csrc[start + i];
            float4 a4 = ad[sn];
            s0 += __expf(lrelu(a4.x + adn.x));
            s1 += __expf(lrelu(a4.y + adn.y));
            s2 += __expf(lrelu(a4.z + adn.z));
        }
#pragma unroll
        for (int o = 32; o > 0; o >>= 1) {
            s0 += __shfl_xor(s0, o, 64);
            s1 += __shfl_xor(s1, o, 64);
            s2 += __shfl_xor(s2, o, 64);
        }
        float i0 = 1.f / s0, i1 = 1.f / s1, i2 = 1.f / s2;
        for (int base = 0; base < deg; base += 64) {
            int cnt = deg - base; if (cnt > 64) cnt = 64;
            if (L < cnt) {
                int sn = csrc[start + base + L];
                float4 a4 = ad[sn];
                slot[wv_][L] = make_float4(__builtin_bit_cast(float, sn),
                                           __expf(lrelu(a4.x + adn.x)) * i0,
                                           __expf(lrelu(a4.y + adn.y)) * i1,
                                           __expf(lrelu(a4.z + adn.z)) * i2);
            }
            __builtin_amdgcn_wave_barrier();
            for (int j = 0; j < cnt; j++) {
                float4 sc = slot[wv_][j];
                int s_n = __builtin_bit_cast(int, sc.x);
                unsigned u = ((const unsigned*)(hb + (size_t)s_n * 128))[L];
                float x0 = bf_lo(u), x1 = bf_hi(u);
                t0.x += sc.y * x0; t0.y += sc.y * x1;
                t1.x += sc.z * x0; t1.y += sc.z * x1;
                t2.x += sc.w * x0; t2.y += sc.w * x1;
            }
            __builtin_amdgcn_wave_barrier();
        }
    }
    o2[L] = t0; o2[64 + L] = t1; o2[128 + L] = t2;
}

// ---------------------------------------------------------------------------
// Full GRU stack: one block per batch element, 768 threads (2 dirs x 384).
// ---------------------------------------------------------------------------
__global__ __launch_bounds__(768) void gru_all(const float* __restrict__ reado,
                                               const int* __restrict__ goffs,
                                               const float* __restrict__ WihT0,
                                               const float* __restrict__ WhhT0,
                                               const float* __restrict__ bih0,
                                               const float* __restrict__ bhh0,
                                               const float* __restrict__ WihT1,
                                               const float* __restrict__ WhhT1,
                                               const float* __restrict__ bih1,
                                               const float* __restrict__ bhh1,
                                               float* __restrict__ out) {
    const int b = blockIdx.x;
    const int tid = threadIdx.x;
    const int dir = tid / 384;
    const int j = tid - dir * 384;
    __shared__ float xs[3][128];
    __shared__ float y0s[3][256];
    __shared__ float hs[2][128];
    __shared__ float gil[2][384], ghl[2][384];
    __shared__ float fin01[2][128];
    if (tid < 128) {
        int cnt = goffs[b + 1] - goffs[b];
        float invc = 1.f / fmaxf((float)cnt, 1.f);
#pragma unroll
        for (int t = 0; t < 3; t++)
            xs[t][tid] = reado[(size_t)t * Bb * Hh + (size_t)b * Hh + tid] * invc;
    }
    if (j < 128) hs[dir][j] = 0.f;
    __syncthreads();
    {
        const float* Wi = WihT0 + (size_t)dir * 128 * 384;
        const float* Wh = WhhT0 + (size_t)dir * 128 * 384;
        float gi[3];
        gi[0] = gi[1] = gi[2] = bih0[dir * 384 + j];
        for (int k = 0; k < 128; k++) {
            float w = Wi[(size_t)k * 384 + j];
            gi[0] += w * xs[0][k]; gi[1] += w * xs[1][k]; gi[2] += w * xs[2][k];
        }
        const float bhj = bhh0[dir * 384 + j];
        for (int step = 0; step < 3; step++) {
            int t = dir ? 2 - step : step;
            float g = bhj;
            for (int k = 0; k < 128; k++) g += Wh[(size_t)k * 384 + j] * hs[dir][k];
            ghl[dir][j] = g;
            gil[dir][j] = gi[t];
            __syncthreads();
            if (j < 128) {
                float r = sigmoidf(gil[dir][j] + ghl[dir][j]);
                float z = sigmoidf(gil[dir][j + 128] + ghl[dir][j + 128]);
                float nn2 = tanhf(gil[dir][j + 256] + r * ghl[dir][j + 256]);
                float hnew = (1.f - z) * nn2 + z * hs[dir][j];
                hs[dir][j] = hnew;
                y0s[t][dir * 128 + j] = hnew;
                if (step == 2) fin01[dir][j] = hnew;
            }
            __syncthreads();
        }
    }
    if (j < 128) hs[dir][j] = 0.f;
    {
        const float* Wi = WihT1 + (size_t)dir * 256 * 384;
        const float* Wh = WhhT1 + (size_t)dir * 128 * 384;
        float gi[3];
        gi[0] = gi[1] = gi[2] = bih1[dir * 384 + j];
        for (int k = 0; k < 256; k++) {
            float w = Wi[(size_t)k * 384 + j];
            gi[0] += w * y0s[0][k]; gi[1] += w * y0s[1][k]; gi[2] += w * y0s[2][k];
        }
        const float bhj = bhh1[dir * 384 + j];
        __syncthreads();
        for (int step = 0; step < 3; step++) {
            int t = dir ? 2 - step : step;
            float g = bhj;
            for (int k = 0; k < 128; k++) g += Wh[(size_t)k * 384 + j] * hs[dir][k];
            ghl[dir][j] = g;
            gil[dir][j] = gi[t];
            __syncthreads();
            if (j < 128) {
                float r = sigmoidf(gil[dir][j] + ghl[dir][j]);
                float z = sigmoidf(gil[dir][j + 128] + ghl[dir][j + 128]);
                float nn2 = tanhf(gil[dir][j + 256] + r * ghl[dir][j + 256]);
                float hnew = (1.f - z) * nn2 + z * hs[dir][j];
                hs[dir][j] = hnew;
                if (step == 2) xs[dir][j] = hnew;
            }
            __syncthreads();
        }
    }
    if (tid < 128)
        out[(size_t)b * Hh + tid] = 0.25f * (fin01[0][tid] + fin01[1][tid] +
                                             xs[0][tid] + xs[1][tid]);
}

// ---------------------------------------------------------------------------
extern "C" void kernel_launch(void* const* d_in, const int* in_sizes, int n_in,
                              void* d_out, int out_size, void* d_ws, size_t ws_size,
                              hipStream_t stream) {
    const float* h      = (const float*)d_in[0];
    const int*   wid    = (const int*)d_in[1];
    const int*   src    = (const int*)d_in[2];
    const int*   dst    = (const int*)d_in[3];
    const int*   gid    = (const int*)d_in[4];
    const float* projW  = (const float*)d_in[5];
    const float* projB  = (const float*)d_in[6];
    const float* convWn = (const float*)d_in[7];
    const float* convBn = (const float*)d_in[8];
    const float* convAtt= (const float*)d_in[9];
    const float* convWs = (const float*)d_in[10];
    const float* convB  = (const float*)d_in[11];
    const float* convG  = (const float*)d_in[12];
    const float* convBe = (const float*)d_in[13];
    const float* Wih0   = (const float*)d_in[14];
    const float* Whh0   = (const float*)d_in[15];
    const float* bih0   = (const float*)d_in[16];
    const float* bhh0   = (const float*)d_in[17];
    const float* Wih1   = (const float*)d_in[18];
    const float* Whh1   = (const float*)d_in[19];
    const float* bih1   = (const float*)d_in[20];
    const float* bhh1   = (const float*)d_in[21];
    float* out = (float*)d_out;

    char* p = (char*)d_ws;
    auto align16 = [&]() { p = (char*)(((uintptr_t)p + 15) & ~(uintptr_t)15); };
    auto alloc_f = [&](size_t n) { align16(); float* r = (float*)p; p += n * sizeof(float); return r; };
    auto alloc_i = [&](size_t n) { align16(); int* r = (int*)p; p += n * sizeof(int); return r; };
    auto alloc_s = [&](size_t n) { align16(); unsigned short* r = (unsigned short*)p; p += n * sizeof(unsigned short); return r; };
    float* hcur  = alloc_f((size_t)Nn * 128);
    float* T     = alloc_f((size_t)Nn * 384);
    float* adbuf = alloc_f((size_t)Nn * 4);
    float* addbuf= alloc_f((size_t)Nn * 4);
    // contiguous zero region: reado | deg
    float* reado = alloc_f((size_t)3 * Bb * Hh);
    int* deg  = alloc_i(Nn);
    const size_t zero_bytes = (size_t)3 * Bb * Hh * sizeof(float) + Nn * sizeof(int);
    float* WihT0 = alloc_f((size_t)2 * 128 * 384);
    float* WhhT0 = alloc_f((size_t)2 * 128 * 384);
    float* WihT1 = alloc_f((size_t)2 * 256 * 384);
    float* WhhT1 = alloc_f((size_t)2 * 128 * 384);
    float* vavd  = alloc_f(1536);
    float* vc    = alloc_f(12);
    float* biasF = alloc_f(256);
    int* offs = alloc_i(Nn + 1);
    int* cur  = alloc_i(Nn);
    int* csrc = alloc_i(Ee);
    int* goffs = alloc_i(Bb + 1);
    unsigned short* hb = alloc_s((size_t)Nn * 128);   // bf16 hcur plane
    unsigned short* pBth = alloc_s(128 * 128);
    unsigned short* pBtl = alloc_s(128 * 128);
    unsigned short* WfTh[2] = { alloc_s(128 * 384), alloc_s(128 * 384) };
    unsigned short* WfTl[2] = { alloc_s(128 * 384), alloc_s(128 * 384) };

    hipMemsetAsync(reado, 0, zero_bytes, stream);

    PrepArgs pa;
    pa.projW = projW + (size_t)Vv * Hh;
    pa.convWn = convWn; pa.convWs = convWs; pa.convAtt = convAtt;
    pa.convBn = convBn; pa.convB = convB;
    pa.Wih0 = Wih0; pa.Whh0 = Whh0; pa.Wih1 = Wih1; pa.Whh1 = Whh1;
    pa.gid = gid; pa.dst = dst;
    pa.pBth = pBth; pa.pBtl = pBtl;
    pa.WfTh0 = WfTh[0]; pa.WfTl0 = WfTl[0]; pa.WfTh1 = WfTh[1]; pa.WfTl1 = WfTl[1];
    pa.vavd = vavd; pa.vc = vc; pa.biasF = biasF;
    pa.WihT0 = WihT0; pa.WhhT0 = WhhT0; pa.WihT1 = WihT1; pa.WhhT1 = WhhT1;
    pa.goffs = goffs; pa.deg = deg;
    const int prep_total = 16384 + 2 * 49152 + 1536 + 12 + 256 + 98304 + 98304 + 196608 + 98304 + Nn + Ee;
    prep_all<<<(prep_total + 255) / 256, 256, 0, stream>>>(pa);

    scan_offsets<<<1, 1024, 0, stream>>>(deg, offs, cur);
    fill_csr<<<1250, 256, 0, stream>>>(dst, src, cur, csrc);

    // projection + dots L0 + hb + readout0
    {
        GArgs g = {};
        g.A = h; g.Bth = pBth; g.Btl = pBtl; g.bias = projB;
        g.M = Nn; g.K = 128;
        g.wid = wid; g.projW = projW; g.hcur = hcur;
        g.gid = gid; g.reado = reado;
        g.vavd = vavd; g.vc = vc; g.adf = adbuf; g.addf = addbuf; g.hb = hb;
        gemm_fused<0><<<dim3(1, Nn / 32), 256, 0, stream>>>(g);
    }

    const int nwaveblocks = (Nn * 64 + 255) / 256;   // 5000
    for (int l = 0; l < 2; l++) {
        gat_gather<<<nwaveblocks, 256, 0, stream>>>(hb, (const float4*)adbuf, (const float4*)addbuf,
                                                    offs, csrc, T);
        {
            GArgs g = {};
            g.A = T; g.Bth = WfTh[l]; g.Btl = WfTl[l]; g.bias = biasF + l * 128;
            g.M = Nn; g.K = 384;
            g.deg = deg; g.gamma = convG + l * Hh; g.beta = convBe + l * Hh;
            g.hcur = hcur;
            g.gid = gid; g.reado = reado + (size_t)(l + 1) * Bb * Hh;
            if (l == 0) { g.vavd = vavd + 768; g.vc = vc + 6; g.adf = adbuf; g.addf = addbuf; g.hb = hb; }
            gemm_fused<2><<<dim3(1, Nn / 32), 256, 0, stream>>>(g);
        }
    }

    gru_all<<<Bb, 768, 0, stream>>>(reado, goffs, WihT0, WhhT0, bih0, bhh0,
                                    WihT1, WhhT1, bih1, bhh1, out);
}

// Round 10
// 371.763 us; speedup vs baseline: 1.5961x; 1.0142x over previous
//
#include <hip/hip_runtime.h>
#include <cstddef>
#include <cstdint>

// Problem constants (from reference)
static constexpr int Nn    = 20000;
static constexpr int Ee    = 320000;
static constexpr int Vv    = 100;
static constexpr int Hh    = 128;
static constexpr int HEADS = 3;
static constexpr int Bb    = 200;
static constexpr float NEG = 0.2f;
static constexpr float EPS = 1e-5f;

typedef short bf16x8 __attribute__((ext_vector_type(8)));
typedef float f32x4  __attribute__((ext_vector_type(4)));

__device__ inline unsigned short bf16_rne(float x) {
    unsigned u = __builtin_bit_cast(unsigned, x);
    u += 0x7FFFu + ((u >> 16) & 1u);
    return (unsigned short)(u >> 16);
}
__device__ inline float bf16_f(unsigned short h) {
    unsigned u = ((unsigned)h) << 16;
    return __builtin_bit_cast(float, u);
}
__device__ inline float bf_lo(unsigned u) { return __builtin_bit_cast(float, u << 16); }
__device__ inline float bf_hi(unsigned u) { return __builtin_bit_cast(float, u & 0xFFFF0000u); }
__device__ inline float lrelu(float a) { return a >= 0.f ? a : NEG * a; }
__device__ inline float sigmoidf(float x) { return 1.f / (1.f + __expf(-x)); }

// ---------------------------------------------------------------------------
// CSR scan + fill (hist lives in prep_all)
// ---------------------------------------------------------------------------
__global__ __launch_bounds__(1024) void scan_offsets(const int* __restrict__ deg,
                                                     int* __restrict__ offs,
                                                     int* __restrict__ cur) {
    __shared__ int sums[1024];
    const int tid = threadIdx.x;
    const int per = (Nn + 1023) >> 10;
    int begin = tid * per;
    int end = begin + per; if (end > Nn) end = Nn;
    if (begin > Nn) begin = Nn;
    int s = 0;
    for (int i = begin; i < end; i++) s += deg[i];
    sums[tid] = s;
    __syncthreads();
    for (int off = 1; off < 1024; off <<= 1) {
        int v = (tid >= off) ? sums[tid - off] : 0;
        __syncthreads();
        sums[tid] += v;
        __syncthreads();
    }
    int run = sums[tid] - s;
    for (int i = begin; i < end; i++) {
        offs[i] = run; cur[i] = run;
        run += deg[i];
    }
    if (end == Nn) offs[Nn] = run;
}

__global__ void fill_csr(const int* __restrict__ dst, const int* __restrict__ src,
                         int* __restrict__ cur, int* __restrict__ csrc) {
    for (int i = blockIdx.x * blockDim.x + threadIdx.x; i < Ee; i += gridDim.x * blockDim.x) {
        int p = atomicAdd(&cur[dst[i]], 1);
        csrc[p] = src[i];
    }
}

// ---------------------------------------------------------------------------
// Fused prep: projW split; Wfused = blockdiag(Wn)@Ws split-transposed;
// va/vd = Wn_h @ att halves; vc = bn_h . att halves; biasF = convB + bn@Ws;
// GRU weight transposes; graph offsets; dst histogram.
// ---------------------------------------------------------------------------
struct PrepArgs {
    const float *projW, *convWn, *convWs, *convAtt, *convBn, *convB;
    const float *Wih0, *Whh0, *Wih1, *Whh1;
    const int *gid, *dst;
    unsigned short *pBth, *pBtl;
    unsigned short *WfTh0, *WfTl0, *WfTh1, *WfTl1;
    float *vavd, *vc, *biasF;
    float *WihT0, *WhhT0, *WihT1, *WhhT1;
    int *goffs, *deg;
};

__device__ inline void wsplit(const float* B, int K, int N, int idx,
                              unsigned short* Bth, unsigned short* Btl) {
    int k = idx / N, n = idx - k * N;
    float v = B[idx];
    unsigned short h = bf16_rne(v);
    unsigned short l = bf16_rne(v - bf16_f(h));
    Bth[(size_t)n * K + k] = h;
    Btl[(size_t)n * K + k] = l;
}
__device__ inline void gruT(const float* W, int K, int idx, float* WT) {
    int d = idx / (384 * K);
    int r = idx - d * 384 * K;
    int j = r / K, k = r - j * K;
    WT[(size_t)d * K * 384 + (size_t)k * 384 + j] = W[idx];
}

__global__ void prep_all(PrepArgs a) {
    int i = blockIdx.x * blockDim.x + threadIdx.x;
    if (i < 16384) { wsplit(a.projW, 128, 128, i, a.pBth, a.pBtl); return; } i -= 16384;
#pragma unroll
    for (int l = 0; l < 2; l++) {
        if (i < 49152) {
            int k = i >> 7, c = i & 127;
            int h = k >> 7, i_ = k & 127;
            const float* wn = a.convWn + (size_t)l * 49152 + (size_t)i_ * 384 + h * 128;
            const float* ws = a.convWs + (size_t)l * 49152 + (size_t)(h * 128) * 128 + c;
            float v = 0.f;
            for (int j = 0; j < 128; j++) v += wn[j] * ws[(size_t)j * 128];
            unsigned short hi = bf16_rne(v);
            unsigned short lo = bf16_rne(v - bf16_f(hi));
            unsigned short* th = l ? a.WfTh1 : a.WfTh0;
            unsigned short* tl = l ? a.WfTl1 : a.WfTl0;
            th[(size_t)c * 384 + k] = hi;
            tl[(size_t)c * 384 + k] = lo;
            return;
        }
        i -= 49152;
    }
    if (i < 1536) {
        int l = i / 768, r = i % 768;
        int sd = r / 384, rr = r % 384, h = rr >> 7, i_ = rr & 127;
        const float* wn = a.convWn + (size_t)l * 49152 + (size_t)i_ * 384 + h * 128;
        const float* at = a.convAtt + l * 768 + h * 256 + sd * 128;
        float v = 0.f;
        for (int j = 0; j < 128; j++) v += wn[j] * at[j];
        a.vavd[i] = v;
        return;
    } i -= 1536;
    if (i < 12) {
        int l = i / 6, r = i % 6, sd = r / 3, h = r % 3;
        const float* bn = a.convBn + l * 384 + h * 128;
        const float* at = a.convAtt + l * 768 + h * 256 + sd * 128;
        float v = 0.f;
        for (int j = 0; j < 128; j++) v += bn[j] * at[j];
        a.vc[i] = v;
        return;
    } i -= 12;
    if (i < 256) {
        int l = i >> 7, c = i & 127;
        const float* bn = a.convBn + l * 384;
        const float* ws = a.convWs + (size_t)l * 49152 + c;
        float v = a.convB[l * 128 + c];
        for (int k = 0; k < 384; k++) v += bn[k] * ws[(size_t)k * 128];
        a.biasF[i] = v;
        return;
    } i -= 256;
    if (i < 98304)  { gruT(a.Wih0, 128, i, a.WihT0); return; }  i -= 98304;
    if (i < 98304)  { gruT(a.Whh0, 128, i, a.WhhT0); return; }  i -= 98304;
    if (i < 196608) { gruT(a.Wih1, 256, i, a.WihT1); return; }  i -= 196608;
    if (i < 98304)  { gruT(a.Whh1, 128, i, a.WhhT1); return; }  i -= 98304;
    if (i < Nn) {
        int g = a.gid[i];
        if (i == 0) { for (int b = 0; b <= g; b++) a.goffs[b] = 0; }
        else { int pg = a.gid[i - 1]; for (int b = pg + 1; b <= g; b++) a.goffs[b] = i; }
        if (i == Nn - 1) { for (int b = g + 1; b <= Bb; b++) a.goffs[b] = Nn; }
        return;
    } i -= Nn;
    if (i < Ee) atomicAdd(&a.deg[a.dst[i]], 1);
}

// ---------------------------------------------------------------------------
// Split-bf16 MFMA GEMM, BM=32, BN=128, BK=32; 256 threads = 4 waves (1x4),
// wave tile 32x32 (2x2 MFMA 16x16x32). Fused epilogues:
// MODE 0: proj: hcur = acc+bias+projW[wid]; MODE 2: residual+LN+ReLU.
// Both: fused per-graph readout; optional next-layer att dots (register-space,
// no LDS conflicts) + bf16 hcur plane.
// ---------------------------------------------------------------------------
struct GArgs {
    const float* A; const unsigned short* Bth; const unsigned short* Btl;
    const float* bias; int M, K;
    const int* wid; const float* projW;                 // MODE 0
    const int* deg; const float* gamma; const float* beta;  // MODE 2
    float* hcur;
    const int* gid; float* reado;
    const float* vavd; const float* vc;                 // null -> skip dots/hb
    float* adf; float* addf;
    unsigned short* hb;
};

template <int MODE>
__global__ __launch_bounds__(256) void gemm_fused(GArgs a) {
    __shared__ unsigned short As_hi[32][40];
    __shared__ unsigned short As_lo[32][40];
    __shared__ unsigned short Bs_hi[128][40];
    __shared__ unsigned short Bs_lo[128][40];
    __shared__ float ytile[32][132];
    __shared__ float sred[6][32][4];
    __shared__ int sgid[32];
    const int tid  = threadIdx.x;
    const int row0 = blockIdx.y * 32;
    const int wn   = tid >> 6;          // wave 0..3 along N
    const int L    = tid & 63;
    const int lrow = L & 15;
    const int lq   = L >> 4;
    const int K = a.K;

    f32x4 acc[2][2];
#pragma unroll
    for (int i = 0; i < 2; i++)
#pragma unroll
        for (int j = 0; j < 2; j++) acc[i][j] = (f32x4){0.f, 0.f, 0.f, 0.f};

    for (int kb = 0; kb < K; kb += 32) {
        {   // stage A 32x32
            int m  = tid >> 3;
            int kq = (tid & 7) * 4;
            float4 v = *(const float4*)(a.A + (size_t)(row0 + m) * K + kb + kq);
            unsigned short h0 = bf16_rne(v.x), h1 = bf16_rne(v.y),
                           h2 = bf16_rne(v.z), h3 = bf16_rne(v.w);
            *(short4*)&As_hi[m][kq] = make_short4((short)h0, (short)h1, (short)h2, (short)h3);
            *(short4*)&As_lo[m][kq] = make_short4((short)bf16_rne(v.x - bf16_f(h0)),
                                                  (short)bf16_rne(v.y - bf16_f(h1)),
                                                  (short)bf16_rne(v.z - bf16_f(h2)),
                                                  (short)bf16_rne(v.w - bf16_f(h3)));
        }
        {   // stage B^T 128x32
            int n  = tid >> 1;
            int kh = (tid & 1) * 16;
            const unsigned short* sh = a.Bth + (size_t)n * K + kb + kh;
            const unsigned short* sl = a.Btl + (size_t)n * K + kb + kh;
            *(float4*)&Bs_hi[n][kh]     = *(const float4*)sh;
            *(float4*)&Bs_hi[n][kh + 8] = *(const float4*)(sh + 8);
            *(float4*)&Bs_lo[n][kh]     = *(const float4*)sl;
            *(float4*)&Bs_lo[n][kh + 8] = *(const float4*)(sl + 8);
        }
        __syncthreads();
        bf16x8 ah[2], al[2], bh[2], bl[2];
#pragma unroll
        for (int mi = 0; mi < 2; mi++) {
            int r = mi * 16 + lrow;
            ah[mi] = *(const bf16x8*)&As_hi[r][lq * 8];
            al[mi] = *(const bf16x8*)&As_lo[r][lq * 8];
        }
#pragma unroll
        for (int ni = 0; ni < 2; ni++) {
            int r = wn * 32 + ni * 16 + lrow;
            bh[ni] = *(const bf16x8*)&Bs_hi[r][lq * 8];
            bl[ni] = *(const bf16x8*)&Bs_lo[r][lq * 8];
        }
#pragma unroll
        for (int mi = 0; mi < 2; mi++)
#pragma unroll
            for (int ni = 0; ni < 2; ni++) {
                acc[mi][ni] = __builtin_amdgcn_mfma_f32_16x16x32_bf16(ah[mi], bh[ni], acc[mi][ni], 0, 0, 0);
                acc[mi][ni] = __builtin_amdgcn_mfma_f32_16x16x32_bf16(ah[mi], bl[ni], acc[mi][ni], 0, 0, 0);
                acc[mi][ni] = __builtin_amdgcn_mfma_f32_16x16x32_bf16(al[mi], bh[ni], acc[mi][ni], 0, 0, 0);
            }
        __syncthreads();
    }

    // bias
#pragma unroll
    for (int ni = 0; ni < 2; ni++) {
        float bb = a.bias[wn * 32 + ni * 16 + lrow];
#pragma unroll
        for (int mi = 0; mi < 2; mi++)
#pragma unroll
            for (int r = 0; r < 4; r++) acc[mi][ni][r] += bb;
    }

    if constexpr (MODE == 0) {
        // acc := y = acc + projW[wid[row]]  (bias already in)
#pragma unroll
        for (int mi = 0; mi < 2; mi++)
#pragma unroll
            for (int r = 0; r < 4; r++) {
                int lr = mi * 16 + lq * 4 + r;
                int row = row0 + lr;
                int wi = a.wid[row];
#pragma unroll
                for (int ni = 0; ni < 2; ni++) {
                    int c = wn * 32 + ni * 16 + lrow;
                    float y = acc[mi][ni][r] + a.projW[(size_t)wi * 128 + c];
                    acc[mi][ni][r] = y;
                    a.hcur[(size_t)row * 128 + c] = y;
                    ytile[lr][c] = y;
                }
            }
    }

    if constexpr (MODE == 2) {
        __shared__ float red1[32][4], red2[32][4];
        float g4[2], be4[2];
#pragma unroll
        for (int ni = 0; ni < 2; ni++) {
            int c = wn * 32 + ni * 16 + lrow;
            g4[ni] = a.gamma[c]; be4[ni] = a.beta[c];
        }
#pragma unroll
        for (int mi = 0; mi < 2; mi++)
#pragma unroll
            for (int r = 0; r < 4; r++) {
                int lr = mi * 16 + lq * 4 + r;
                int row = row0 + lr;
                int dg = a.deg[row];
#pragma unroll
                for (int ni = 0; ni < 2; ni++) {
                    int c = wn * 32 + ni * 16 + lrow;
                    float hold = a.hcur[(size_t)row * 128 + c];
                    acc[mi][ni][r] = hold + (dg > 0 ? acc[mi][ni][r] : 0.f);
                }
            }
#pragma unroll
        for (int mi = 0; mi < 2; mi++)
#pragma unroll
            for (int r = 0; r < 4; r++) {
                float ps = acc[mi][0][r] + acc[mi][1][r];
#pragma unroll
                for (int o = 1; o < 16; o <<= 1) ps += __shfl_xor(ps, o, 64);
                if (lrow == 0) red1[mi * 16 + lq * 4 + r][wn] = ps;
            }
        __syncthreads();
#pragma unroll
        for (int mi = 0; mi < 2; mi++)
#pragma unroll
            for (int r = 0; r < 4; r++) {
                int lr = mi * 16 + lq * 4 + r;
                float mu = (red1[lr][0] + red1[lr][1] + red1[lr][2] + red1[lr][3]) * (1.f / 128.f);
                float qs = 0.f;
#pragma unroll
                for (int ni = 0; ni < 2; ni++) {
                    float dx = acc[mi][ni][r] - mu;
                    qs += dx * dx;
                }
#pragma unroll
                for (int o = 1; o < 16; o <<= 1) qs += __shfl_xor(qs, o, 64);
                if (lrow == 0) red2[lr][wn] = qs;
            }
        __syncthreads();
#pragma unroll
        for (int mi = 0; mi < 2; mi++)
#pragma unroll
            for (int r = 0; r < 4; r++) {
                int lr = mi * 16 + lq * 4 + r;
                int row = row0 + lr;
                float mu = (red1[lr][0] + red1[lr][1] + red1[lr][2] + red1[lr][3]) * (1.f / 128.f);
                float var = (red2[lr][0] + red2[lr][1] + red2[lr][2] + red2[lr][3]) * (1.f / 128.f);
                float rs = rsqrtf(var + EPS);
#pragma unroll
                for (int ni = 0; ni < 2; ni++) {
                    int c = wn * 32 + ni * 16 + lrow;
                    float y = fmaxf((acc[mi][ni][r] - mu) * rs * g4[ni] + be4[ni], 0.f);
                    acc[mi][ni][r] = y;
                    a.hcur[(size_t)row * 128 + c] = y;
                    ytile[lr][c] = y;
                }
            }
    }

    if (tid < 32) sgid[tid] = a.gid[row0 + tid];

    // ---- register-space attention dots (no ytile loop, no global v loop) ----
    const bool dots = (a.vavd != nullptr);
    if (dots) {
        float vv0[6], vv1[6];
#pragma unroll
        for (int d = 0; d < 6; d++) {
            vv0[d] = a.vavd[d * 128 + wn * 32 + lrow];
            vv1[d] = a.vavd[d * 128 + wn * 32 + 16 + lrow];
        }
#pragma unroll
        for (int d = 0; d < 6; d++) {
#pragma unroll
            for (int mi = 0; mi < 2; mi++)
#pragma unroll
                for (int r = 0; r < 4; r++) {
                    float ps = acc[mi][0][r] * vv0[d] + acc[mi][1][r] * vv1[d];
#pragma unroll
                    for (int o = 1; o < 16; o <<= 1) ps += __shfl_xor(ps, o, 64);
                    if (lrow == 0) sred[d][mi * 16 + lq * 4 + r][wn] = ps;
                }
        }
    }
    __syncthreads();

    // fused per-graph readout (gid sorted -> runs, atomic per run)
    {
        int j = tid & 127, hh = tid >> 7;
        float sum = 0.f; int curg = -1;
        for (int r = hh * 16; r < hh * 16 + 16; r++) {
            int g = sgid[r];
            if (g != curg) {
                if (curg >= 0) atomicAdd(&a.reado[(size_t)curg * 128 + j], sum);
                sum = 0.f; curg = g;
            }
            sum += ytile[r][j];
        }
        if (curg >= 0) atomicAdd(&a.reado[(size_t)curg * 128 + j], sum);
    }

    if (dots) {
        if (tid < 192) {
            int row = tid & 31, d = tid >> 5;     // d in [0,6)
            float s = sred[d][row][0] + sred[d][row][1] + sred[d][row][2] + sred[d][row][3]
                    + a.vc[d];
            int node = row0 + row;
            int sd = d / 3, h = d - sd * 3;
            float* dstp = sd ? a.addf : a.adf;
            dstp[(size_t)node * 4 + h] = s;
        }
        {   // bf16 hcur plane from ytile (<=2-way bank aliasing, free)
            int row = tid >> 3, c0 = (tid & 7) * 16;
            unsigned* dst = (unsigned*)(a.hb + (size_t)(row0 + row) * 128 + c0);
#pragma unroll
            for (int q = 0; q < 8; q++) {
                unsigned lo = bf16_rne(ytile[row][c0 + 2 * q]);
                unsigned hi = bf16_rne(ytile[row][c0 + 2 * q + 1]);
                dst[q] = lo | (hi << 16);
            }
        }
    }
}

// ---------------------------------------------------------------------------
// GAT gather: one wave per dst node, bf16 hcur rows (256B), scores from dots.
// ---------------------------------------------------------------------------
__global__ __launch_bounds__(256) void gat_gather(const unsigned short* __restrict__ hb,
                                                  const float4* __restrict__ ad,
                                                  const float4* __restrict__ add,
                                                  const int* __restrict__ offs,
                                                  const int* __restrict__ csrc,
                                                  float* __restrict__ T) {
    __shared__ float4 slot[4][64];
    const int n = (blockIdx.x * 256 + threadIdx.x) >> 6;
    const int wv_ = threadIdx.x >> 6;
    const int L = threadIdx.x & 63;
    if (n >= Nn) return;
    const int start = offs[n];
    const int deg = offs[n + 1] - start;
    float2* o2 = (float2*)(T + (size_t)n * 384);
    if (deg == 0) {
        float2 z = make_float2(0.f, 0.f);
        o2[L] = z; o2[64 + L] = z; o2[128 + L] = z;
        return;
    }
    const float4 adn = add[n];
    float2 t0 = make_float2(0.f, 0.f), t1 = t0, t2 = t0;

    if (deg <= 64) {
        int sn = 0; float e0 = 0.f, e1 = 0.f, e2 = 0.f;
        if (L < deg) {
            sn = csrc[start + L];
            float4 a4 = ad[sn];
            e0 = __expf(lrelu(a4.x + adn.x));
            e1 = __expf(lrelu(a4.y + adn.y));
            e2 = __expf(lrelu(a4.z + adn.z));
        }
        float s0 = e0, s1 = e1, s2 = e2;
#pragma unroll
        for (int o = 32; o > 0; o >>= 1) {
            s0 += __shfl_xor(s0, o, 64);
            s1 += __shfl_xor(s1, o, 64);
            s2 += __shfl_xor(s2, o, 64);
        }
        slot[wv_][L] = make_float4(__builtin_bit_cast(float, sn),
                                   e0 / s0, e1 / s1, e2 / s2);
        __builtin_amdgcn_wave_barrier();
#pragma unroll 2
        for (int j = 0; j < deg; j++) {
            float4 sc = slot[wv_][j];
            int s_n = __builtin_bit_cast(int, sc.x);
            unsigned u = ((const unsigned*)(hb + (size_t)s_n * 128))[L];
            float x0 = bf_lo(u), x1 = bf_hi(u);
            t0.x += sc.y * x0; t0.y += sc.y * x1;
            t1.x += sc.z * x0; t1.y += sc.z * x1;
            t2.x += sc.w * x0; t2.y += sc.w * x1;
        }
    } else {
        float s0 = 0.f, s1 = 0.f, s2 = 0.f;
        for (int i = L; i < deg; i += 64) {
            int sn = csrc[start + i];
            float4 a4 = ad[sn];
            s0 += __expf(lrelu(a4.x + adn.x));
            s1 += __expf(lrelu(a4.y + adn.y));
            s2 += __expf(lrelu(a4.z + adn.z));
        }
#pragma unroll
        for (int o = 32; o > 0; o >>= 1) {
            s0 += __shfl_xor(s0, o, 64);
            s1 += __shfl_xor(s1, o, 64);
            s2 += __shfl_xor(s2, o, 64);
        }
        float i0 = 1.f / s0, i1 = 1.f / s1, i2 = 1.f / s2;
        for (int base = 0; base < deg; base += 64) {
            int cnt = deg - base; if (cnt > 64) cnt = 64;
            if (L < cnt) {
                int sn = csrc[start + base + L];
                float4 a4 = ad[sn];
                slot[wv_][L] = make_float4(__builtin_bit_cast(float, sn),
                                           __expf(lrelu(a4.x + adn.x)) * i0,
                                           __expf(lrelu(a4.y + adn.y)) * i1,
                                           __expf(lrelu(a4.z + adn.z)) * i2);
            }
            __builtin_amdgcn_wave_barrier();
            for (int j = 0; j < cnt; j++) {
                float4 sc = slot[wv_][j];
                int s_n = __builtin_bit_cast(int, sc.x);
                unsigned u = ((const unsigned*)(hb + (size_t)s_n * 128))[L];
                float x0 = bf_lo(u), x1 = bf_hi(u);
                t0.x += sc.y * x0; t0.y += sc.y * x1;
                t1.x += sc.z * x0; t1.y += sc.z * x1;
                t2.x += sc.w * x0; t2.y += sc.w * x1;
            }
            __builtin_amdgcn_wave_barrier();
        }
    }
    o2[L] = t0; o2[64 + L] = t1; o2[128 + L] = t2;
}

// ---------------------------------------------------------------------------
// Full GRU stack: one block per batch element, 768 threads (2 dirs x 384).
// ---------------------------------------------------------------------------
__global__ __launch_bounds__(768) void gru_all(const float* __restrict__ reado,
                                               const int* __restrict__ goffs,
                                               const float* __restrict__ WihT0,
                                               const float* __restrict__ WhhT0,
                                               const float* __restrict__ bih0,
                                               const float* __restrict__ bhh0,
                                               const float* __restrict__ WihT1,
                                               const float* __restrict__ WhhT1,
                                               const float* __restrict__ bih1,
                                               const float* __restrict__ bhh1,
                                               float* __restrict__ out) {
    const int b = blockIdx.x;
    const int tid = threadIdx.x;
    const int dir = tid / 384;
    const int j = tid - dir * 384;
    __shared__ float xs[3][128];
    __shared__ float y0s[3][256];
    __shared__ float hs[2][128];
    __shared__ float gil[2][384], ghl[2][384];
    __shared__ float fin01[2][128];
    if (tid < 128) {
        int cnt = goffs[b + 1] - goffs[b];
        float invc = 1.f / fmaxf((float)cnt, 1.f);
#pragma unroll
        for (int t = 0; t < 3; t++)
            xs[t][tid] = reado[(size_t)t * Bb * Hh + (size_t)b * Hh + tid] * invc;
    }
    if (j < 128) hs[dir][j] = 0.f;
    __syncthreads();
    {
        const float* Wi = WihT0 + (size_t)dir * 128 * 384;
        const float* Wh = WhhT0 + (size_t)dir * 128 * 384;
        float gi[3];
        gi[0] = gi[1] = gi[2] = bih0[dir * 384 + j];
        for (int k = 0; k < 128; k++) {
            float w = Wi[(size_t)k * 384 + j];
            gi[0] += w * xs[0][k]; gi[1] += w * xs[1][k]; gi[2] += w * xs[2][k];
        }
        const float bhj = bhh0[dir * 384 + j];
        for (int step = 0; step < 3; step++) {
            int t = dir ? 2 - step : step;
            float g = bhj;
            for (int k = 0; k < 128; k++) g += Wh[(size_t)k * 384 + j] * hs[dir][k];
            ghl[dir][j] = g;
            gil[dir][j] = gi[t];
            __syncthreads();
            if (j < 128) {
                float r = sigmoidf(gil[dir][j] + ghl[dir][j]);
                float z = sigmoidf(gil[dir][j + 128] + ghl[dir][j + 128]);
                float nn2 = tanhf(gil[dir][j + 256] + r * ghl[dir][j + 256]);
                float hnew = (1.f - z) * nn2 + z * hs[dir][j];
                hs[dir][j] = hnew;
                y0s[t][dir * 128 + j] = hnew;
                if (step == 2) fin01[dir][j] = hnew;
            }
            __syncthreads();
        }
    }
    if (j < 128) hs[dir][j] = 0.f;
    {
        const float* Wi = WihT1 + (size_t)dir * 256 * 384;
        const float* Wh = WhhT1 + (size_t)dir * 128 * 384;
        float gi[3];
        gi[0] = gi[1] = gi[2] = bih1[dir * 384 + j];
        for (int k = 0; k < 256; k++) {
            float w = Wi[(size_t)k * 384 + j];
            gi[0] += w * y0s[0][k]; gi[1] += w * y0s[1][k]; gi[2] += w * y0s[2][k];
        }
        const float bhj = bhh1[dir * 384 + j];
        __syncthreads();
        for (int step = 0; step < 3; step++) {
            int t = dir ? 2 - step : step;
            float g = bhj;
            for (int k = 0; k < 128; k++) g += Wh[(size_t)k * 384 + j] * hs[dir][k];
            ghl[dir][j] = g;
            gil[dir][j] = gi[t];
            __syncthreads();
            if (j < 128) {
                float r = sigmoidf(gil[dir][j] + ghl[dir][j]);
                float z = sigmoidf(gil[dir][j + 128] + ghl[dir][j + 128]);
                float nn2 = tanhf(gil[dir][j + 256] + r * ghl[dir][j + 256]);
                float hnew = (1.f - z) * nn2 + z * hs[dir][j];
                hs[dir][j] = hnew;
                if (step == 2) xs[dir][j] = hnew;
            }
            __syncthreads();
        }
    }
    if (tid < 128)
        out[(size_t)b * Hh + tid] = 0.25f * (fin01[0][tid] + fin01[1][tid] +
                                             xs[0][tid] + xs[1][tid]);
}

// ---------------------------------------------------------------------------
extern "C" void kernel_launch(void* const* d_in, const int* in_sizes, int n_in,
                              void* d_out, int out_size, void* d_ws, size_t ws_size,
                              hipStream_t stream) {
    const float* h      = (const float*)d_in[0];
    const int*   wid    = (const int*)d_in[1];
    const int*   src    = (const int*)d_in[2];
    const int*   dst    = (const int*)d_in[3];
    const int*   gid    = (const int*)d_in[4];
    const float* projW  = (const float*)d_in[5];
    const float* projB  = (const float*)d_in[6];
    const float* convWn = (const float*)d_in[7];
    const float* convBn = (const float*)d_in[8];
    const float* convAtt= (const float*)d_in[9];
    const float* convWs = (const float*)d_in[10];
    const float* convB  = (const float*)d_in[11];
    const float* convG  = (const float*)d_in[12];
    const float* convBe = (const float*)d_in[13];
    const float* Wih0   = (const float*)d_in[14];
    const float* Whh0   = (const float*)d_in[15];
    const float* bih0   = (const float*)d_in[16];
    const float* bhh0   = (const float*)d_in[17];
    const float* Wih1   = (const float*)d_in[18];
    const float* Whh1   = (const float*)d_in[19];
    const float* bih1   = (const float*)d_in[20];
    const float* bhh1   = (const float*)d_in[21];
    float* out = (float*)d_out;

    char* p = (char*)d_ws;
    auto align16 = [&]() { p = (char*)(((uintptr_t)p + 15) & ~(uintptr_t)15); };
    auto alloc_f = [&](size_t n) { align16(); float* r = (float*)p; p += n * sizeof(float); return r; };
    auto alloc_i = [&](size_t n) { align16(); int* r = (int*)p; p += n * sizeof(int); return r; };
    auto alloc_s = [&](size_t n) { align16(); unsigned short* r = (unsigned short*)p; p += n * sizeof(unsigned short); return r; };
    float* hcur  = alloc_f((size_t)Nn * 128);
    float* T     = alloc_f((size_t)Nn * 384);
    float* adbuf = alloc_f((size_t)Nn * 4);
    float* addbuf= alloc_f((size_t)Nn * 4);
    // contiguous zero region: reado | deg
    float* reado = alloc_f((size_t)3 * Bb * Hh);
    int* deg  = alloc_i(Nn);
    const size_t zero_bytes = (size_t)3 * Bb * Hh * sizeof(float) + Nn * sizeof(int);
    float* WihT0 = alloc_f((size_t)2 * 128 * 384);
    float* WhhT0 = alloc_f((size_t)2 * 128 * 384);
    float* WihT1 = alloc_f((size_t)2 * 256 * 384);
    float* WhhT1 = alloc_f((size_t)2 * 128 * 384);
    float* vavd  = alloc_f(1536);
    float* vc    = alloc_f(12);
    float* biasF = alloc_f(256);
    int* offs = alloc_i(Nn + 1);
    int* cur  = alloc_i(Nn);
    int* csrc = alloc_i(Ee);
    int* goffs = alloc_i(Bb + 1);
    unsigned short* hb = alloc_s((size_t)Nn * 128);   // bf16 hcur plane
    unsigned short* pBth = alloc_s(128 * 128);
    unsigned short* pBtl = alloc_s(128 * 128);
    unsigned short* WfTh[2] = { alloc_s(128 * 384), alloc_s(128 * 384) };
    unsigned short* WfTl[2] = { alloc_s(128 * 384), alloc_s(128 * 384) };

    hipMemsetAsync(reado, 0, zero_bytes, stream);

    PrepArgs pa;
    pa.projW = projW + (size_t)Vv * Hh;
    pa.convWn = convWn; pa.convWs = convWs; pa.convAtt = convAtt;
    pa.convBn = convBn; pa.convB = convB;
    pa.Wih0 = Wih0; pa.Whh0 = Whh0; pa.Wih1 = Wih1; pa.Whh1 = Whh1;
    pa.gid = gid; pa.dst = dst;
    pa.pBth = pBth; pa.pBtl = pBtl;
    pa.WfTh0 = WfTh[0]; pa.WfTl0 = WfTl[0]; pa.WfTh1 = WfTh[1]; pa.WfTl1 = WfTl[1];
    pa.vavd = vavd; pa.vc = vc; pa.biasF = biasF;
    pa.WihT0 = WihT0; pa.WhhT0 = WhhT0; pa.WihT1 = WihT1; pa.WhhT1 = WhhT1;
    pa.goffs = goffs; pa.deg = deg;
    const int prep_total = 16384 + 2 * 49152 + 1536 + 12 + 256 + 98304 + 98304 + 196608 + 98304 + Nn + Ee;
    prep_all<<<(prep_total + 255) / 256, 256, 0, stream>>>(pa);

    scan_offsets<<<1, 1024, 0, stream>>>(deg, offs, cur);
    fill_csr<<<1250, 256, 0, stream>>>(dst, src, cur, csrc);

    // projection + dots L0 + hb + readout0
    {
        GArgs g = {};
        g.A = h; g.Bth = pBth; g.Btl = pBtl; g.bias = projB;
        g.M = Nn; g.K = 128;
        g.wid = wid; g.projW = projW; g.hcur = hcur;
        g.gid = gid; g.reado = reado;
        g.vavd = vavd; g.vc = vc; g.adf = adbuf; g.addf = addbuf; g.hb = hb;
        gemm_fused<0><<<dim3(1, Nn / 32), 256, 0, stream>>>(g);
    }

    const int nwaveblocks = (Nn * 64 + 255) / 256;   // 5000
    for (int l = 0; l < 2; l++) {
        gat_gather<<<nwaveblocks, 256, 0, stream>>>(hb, (const float4*)adbuf, (const float4*)addbuf,
                                                    offs, csrc, T);
        {
            GArgs g = {};
            g.A = T; g.Bth = WfTh[l]; g.Btl = WfTl[l]; g.bias = biasF + l * 128;
            g.M = Nn; g.K = 384;
            g.deg = deg; g.gamma = convG + l * Hh; g.beta = convBe + l * Hh;
            g.hcur = hcur;
            g.gid = gid; g.reado = reado + (size_t)(l + 1) * Bb * Hh;
            if (l == 0) { g.vavd = vavd + 768; g.vc = vc + 6; g.adf = adbuf; g.addf = addbuf; g.hb = hb; }
            gemm_fused<2><<<dim3(1, Nn / 32), 256, 0, stream>>>(g);
        }
    }

    gru_all<<<Bb, 768, 0, stream>>>(reado, goffs, WihT0, WhhT0, bih0, bhh0,
                                    WihT1, WhhT1, bih1, bhh1, out);
}